// Round 9
// baseline (221.472 us; speedup 1.0000x reference)
//
#include <hip/hip_runtime.h>
#include <hip/hip_fp16.h>
#include <math.h>

#define NB 32
#define NL 512
#define NC 64
#define NG 3
#define NT 10000
#define NP 96
#define TOPM 20
#define M1 8      // per-lane per-chunk fp32 prefilter list
#define NCH 256   // t-chunks (250 real, 6 empty)
#define CHUNK 40
#define QK 16     // extracted per quarter (4 quarters -> 64 candidates)
#define NCAND 64
#define PNBLK 1250   // pnorm blocks (NT*NC/512)
#define TRBLK 5000   // transpose blocks (4 c-tiles interleaved x 1250 t-tiles)
#define CSTR 786     // LDS c-stride (floats): 4*CSTR%32==8 -> <=2-way banks
#define GSTR ((size_t)NT * NC * 4)  // float stride between g-planes

// ---------------------------------------------------------------------------
// Kernel 1 (prep, 3 classes): [0,NB) qstat | [NB,NB+PNBLK) pnorm32 |
// [NB+PNBLK,..) y-transpose to fp16 yT[c][t][p].
// Transpose block order: C0 = (tb&3)*16 so the 4 complementary 64B-line
// streams are adjacent blocks -> DRAM sees a sequential walk (R8 fix).
// ---------------------------------------------------------------------------
__global__ __launch_bounds__(512) void prep_kernel(
    const float* __restrict__ x, const float* __restrict__ ps,
    const float* __restrict__ y, double* __restrict__ q,
    float* __restrict__ phat, __half* __restrict__ yt16) {
  __shared__ __align__(16) char smem[16 * CSTR * 4];  // 50304 B
  if (blockIdx.x < NB) {
    // ---- qstat (R5-R8-proven math) ----
    double* s_sum = (double*)smem;        // [w][g][c] : w*192+g*64+c
    double* s_sq = s_sum + 1536;
    double* s_abs = s_sq + 1536;
    double* s_first = s_abs + 1536;       // [g][c]
    double* s_last = s_first + 192;
    const int b = blockIdx.x, w = threadIdx.x >> 6, c = threadIdx.x & 63;
    const float* xp = x + (size_t)b * NL * NC + c;
    const int l0 = w * 64;
    double sum[3] = {0, 0, 0}, sumsq[3] = {0, 0, 0}, sumabs[3] = {0, 0, 0};
    double prev[3] = {0, 0, 0}, first[3] = {0, 0, 0};
    if (w > 0) {
      double e0 = xp[(l0 - 4) * NC], e1 = xp[(l0 - 3) * NC];
      double e2 = xp[(l0 - 2) * NC], e3 = xp[(l0 - 1) * NC];
      prev[2] = e3; prev[1] = (e2 + e3) * 0.5; prev[0] = (e0 + e1 + e2 + e3) * 0.25;
    }
    double acc2 = 0.0, acc4 = 0.0;
    for (int i = 0; i < 64; ++i) {
      const int l = l0 + i;
      double v = (double)xp[l * NC];
      sum[2] += v; sumsq[2] += v * v;
      if (l == 0) first[2] = v; else sumabs[2] += fabs(v - prev[2]);
      prev[2] = v;
      acc2 += v;
      if (l & 1) {
        double cur = acc2 * 0.5; acc2 = 0.0;
        sum[1] += cur; sumsq[1] += cur * cur;
        if (l == 1) first[1] = cur; else sumabs[1] += fabs(cur - prev[1]);
        prev[1] = cur;
      }
      acc4 += v;
      if ((l & 3) == 3) {
        double cur = acc4 * 0.25; acc4 = 0.0;
        sum[0] += cur; sumsq[0] += cur * cur;
        if (l == 3) first[0] = cur; else sumabs[0] += fabs(cur - prev[0]);
        prev[0] = cur;
      }
    }
    for (int g = 0; g < 3; ++g) {
      s_sum[w * 192 + g * 64 + c] = sum[g];
      s_sq[w * 192 + g * 64 + c] = sumsq[g];
      s_abs[w * 192 + g * 64 + c] = sumabs[g];
    }
    if (w == 0) { for (int g = 0; g < 3; ++g) s_first[g * 64 + c] = first[g]; }
    if (w == 7) { for (int g = 0; g < 3; ++g) s_last[g * 64 + c] = prev[g]; }
    __syncthreads();
    if (w == 0) {
      const double J[3] = {128.0, 256.0, 512.0};
      for (int g = 0; g < 3; ++g) {
        double S = 0, Q2 = 0, A = 0;
        for (int ww = 0; ww < 8; ++ww) {
          S += s_sum[ww * 192 + g * 64 + c];
          Q2 += s_sq[ww * 192 + g * 64 + c];
          A += s_abs[ww * 192 + g * 64 + c];
        }
        double mean = S / J[g];
        double var = Q2 / J[g] - mean * mean; if (var < 0.0) var = 0.0;
        double last = s_last[g * 64 + c];
        double s0 = mean - last;
        double s1 = sqrt(var);
        double s2 = (last - s_first[g * 64 + c]) * (1.0 / 511.0);
        double s3 = A * (1.0 / 511.0);
        double n = sqrt(s0 * s0 + s1 * s1 + s2 * s2 + s3 * s3);
        double inv = 1.0 / fmax(n, 1e-12);
        double* qp = q + ((((size_t)g * NB) + b) * NC + c) * 4;
        qp[0] = s0 * inv; qp[1] = s1 * inv; qp[2] = s2 * inv; qp[3] = s3 * inv;
      }
    }
  } else if (blockIdx.x < NB + PNBLK) {
    // ---- pnorm32 (R6-proven) ----
    const int i = (blockIdx.x - NB) * 512 + threadIdx.x;  // over T*C
    if (i < NT * NC) {
      const int t = i >> 6, c = i & 63;
#pragma unroll
      for (int g = 0; g < 3; ++g) {
        const size_t off = ((((size_t)g * NT) + t) * NC + c) * 4;
        const float4 pv = *reinterpret_cast<const float4*>(ps + off);
        double p0 = pv.x, p1 = pv.y, p2 = pv.z, p3 = pv.w;
        double inv = 1.0 / fmax(sqrt(p0 * p0 + p1 * p1 + p2 * p2 + p3 * p3), 1e-12);
        float4 o;
        o.x = (float)(p0 * inv); o.y = (float)(p1 * inv);
        o.z = (float)(p2 * inv); o.w = (float)(p3 * inv);
        *reinterpret_cast<float4*>(phat + off) = o;
      }
    }
  } else {
    // ---- y transpose: yT16[c][t][p] = fp16(y[t][p][c]) ----
    float* lds = (float*)smem;  // [16 c][CSTR] : c*CSTR + t*98 + p
    const int tb = blockIdx.x - NB - PNBLK;
    const int C0 = (tb & 3) * 16;        // interleaved: siblings adjacent
    const int T0 = (tb >> 2) * 8;
    for (int i = threadIdx.x; i < 3072; i += 512) {  // cq(4) x p(96) x t(8)
      const int cq = i & 3, p = (i >> 2) % 96, t = i / 384;
      const float4 v = *reinterpret_cast<const float4*>(
          y + ((size_t)(T0 + t) * NP + p) * NC + C0 + cq * 4);
      const int cb = cq * 4;
      lds[(cb + 0) * CSTR + t * 98 + p] = v.x;
      lds[(cb + 1) * CSTR + t * 98 + p] = v.y;
      lds[(cb + 2) * CSTR + t * 98 + p] = v.z;
      lds[(cb + 3) * CSTR + t * 98 + p] = v.w;
    }
    __syncthreads();
    for (int j = threadIdx.x; j < 6144; j += 512) {  // c(16) x t(8) x p2(48)
      const int p2 = j % 48, t = (j / 48) & 7, c = j / 384;
      const float2 ab = *reinterpret_cast<const float2*>(
          &lds[c * CSTR + t * 98 + p2 * 2]);
      const __half2 h = __halves2half2(__float2half_rn(ab.x), __float2half_rn(ab.y));
      *reinterpret_cast<__half2*>(
          yt16 + ((size_t)(C0 + c) * NT + T0 + t) * NP + p2 * 2) = h;
    }
  }
}

__device__ __forceinline__ void insert8(float s, int ti, float val[M1], int idx[M1]) {
  float cv = s; int ci = ti;
#pragma unroll
  for (int m = 0; m < M1; ++m) {
    bool sw = cv > val[m];
    float tv = sw ? val[m] : cv; int tx = sw ? idx[m] : ci;
    val[m] = sw ? cv : val[m];   idx[m] = sw ? ci : idx[m];
    cv = tv; ci = tx;
  }
}

// ---------------------------------------------------------------------------
// Kernel 2: fp32 prefilter scan (R6-proven verbatim). 1024-thr blocks = 16
// waves = 16 b's sharing one chunk stream; grid (2, NCH); LB(1024,8).
// ---------------------------------------------------------------------------
__global__ __launch_bounds__(1024, 8) void sim32_kernel(
    const float* __restrict__ phat, const double* __restrict__ q,
    float* __restrict__ cval, int* __restrict__ cidx) {
  const int wav = threadIdx.x >> 6;
  const int c = threadIdx.x & 63;
  const int b = blockIdx.x * 16 + wav;
  const int ch = blockIdx.y;
  float qv[12];
#pragma unroll
  for (int g = 0; g < 3; ++g) {
    const double* qp = q + ((((size_t)g * NB) + b) * NC + c) * 4;
#pragma unroll
    for (int j = 0; j < 4; ++j) qv[g * 4 + j] = (float)(qp[j] * (1.0 / 3.0));
  }
  float val[M1]; int idx[M1];
#pragma unroll
  for (int m = 0; m < M1; ++m) { val[m] = -1e30f; idx[m] = 0; }
  int t0 = ch * CHUNK;
  int t1 = t0 + CHUNK; if (t1 > NT) t1 = NT;
  for (int t = t0; t + 1 < t1; t += 2) {
    const size_t oA = ((size_t)t * NC + c) * 4;
    const size_t oB = oA + (size_t)NC * 4;
    const float4 a0 = *reinterpret_cast<const float4*>(phat + oA);
    const float4 a1 = *reinterpret_cast<const float4*>(phat + GSTR + oA);
    const float4 a2 = *reinterpret_cast<const float4*>(phat + 2 * GSTR + oA);
    const float4 b0 = *reinterpret_cast<const float4*>(phat + oB);
    const float4 b1 = *reinterpret_cast<const float4*>(phat + GSTR + oB);
    const float4 b2 = *reinterpret_cast<const float4*>(phat + 2 * GSTR + oB);
    float sA = qv[0] * a0.x + qv[1] * a0.y + qv[2] * a0.z + qv[3] * a0.w +
               qv[4] * a1.x + qv[5] * a1.y + qv[6] * a1.z + qv[7] * a1.w +
               qv[8] * a2.x + qv[9] * a2.y + qv[10] * a2.z + qv[11] * a2.w;
    float sB = qv[0] * b0.x + qv[1] * b0.y + qv[2] * b0.z + qv[3] * b0.w +
               qv[4] * b1.x + qv[5] * b1.y + qv[6] * b1.z + qv[7] * b1.w +
               qv[8] * b2.x + qv[9] * b2.y + qv[10] * b2.z + qv[11] * b2.w;
    if (sA > val[M1 - 1]) insert8(sA, t, val, idx);
    if (sB > val[M1 - 1]) insert8(sB, t + 1, val, idx);
  }
  float* vo = cval + ((((size_t)b * NC) + c) * NCH + ch) * M1;
  int* io = cidx + ((((size_t)b * NC) + c) * NCH + ch) * M1;
#pragma unroll
  for (int m = 0; m < M1; ++m) { vo[m] = val[m]; io[m] = idx[m]; }
}

// order-preserving fp32 -> u32 map; key = (v asc-map << 32) | (MAX - t)
// so u64-descending == (v desc, t asc). t unique per row => unique keys.
__device__ __forceinline__ unsigned long long mk_key(float v, int t) {
  unsigned u = __float_as_uint(v);
  u = (u & 0x80000000u) ? ~u : (u | 0x80000000u);
  return ((unsigned long long)u << 32) | (unsigned long long)(0xFFFFFFFFu - (unsigned)t);
}

// ---------------------------------------------------------------------------
// Kernel 3: merge + fp64 rerank (validated arithmetic) + softmax + COALESCED
// fp16 gather from yT16. Block = (c,b), 128 threads. (R8-proven.)
// ---------------------------------------------------------------------------
__global__ __launch_bounds__(128) void merge_gather_kernel(
    const float* __restrict__ cval, const int* __restrict__ cidx,
    const float* __restrict__ ps, const double* __restrict__ q,
    const __half* __restrict__ yt16, float* __restrict__ out) {
  const int c = blockIdx.x, b = blockIdx.y;
  __shared__ float v_s[NCH * M1];
  __shared__ int i_s[NCH * M1];
  __shared__ int ct_s[NCAND];
  __shared__ double rv_s[NCAND];
  __shared__ double m0_s, inv_s;
  __shared__ double e_s[TOPM];
  __shared__ int ts_s[TOPM];
  __shared__ float w_s[TOPM];
  const int n = NCH * M1;  // 2048
  const size_t row = (size_t)b * NC + c;
  const float4* vin = reinterpret_cast<const float4*>(cval + row * n);
  const int4* iin = reinterpret_cast<const int4*>(cidx + row * n);
  for (int k = threadIdx.x; k < n / 4; k += 128) {
    *reinterpret_cast<float4*>(&v_s[k * 4]) = vin[k];
    *reinterpret_cast<int4*>(&i_s[k * 4]) = iin[k];
  }
  __syncthreads();
  // --- quarter extraction: all 128 threads; quarter = (w<<1)|(lane>>5) ---
  {
    const int w = threadIdx.x >> 6, lane = threadIdx.x & 63;
    const int lane32 = lane & 31;
    const int qtr = (w << 1) | (lane >> 5);
    const int l0 = (qtr * 64 + lane32 * 2) * M1;
    const int l1 = l0 + M1;
    int p0 = 0, p1 = 0;
    unsigned long long k0 = mk_key(v_s[l0], i_s[l0]);
    unsigned long long k1 = mk_key(v_s[l1], i_s[l1]);
    for (int r = 0; r < QK; ++r) {
      unsigned long long me = k0 > k1 ? k0 : k1;
      unsigned long long km = me;
#pragma unroll
      for (int st = 1; st < 32; st <<= 1) {
        unsigned long long k2 = __shfl_xor(km, st);
        km = k2 > km ? k2 : km;
      }
      if (lane32 == r)
        ct_s[qtr * QK + r] = (int)(0xFFFFFFFFu - (unsigned)(km & 0xFFFFFFFFull));
      if (me == km) {  // unique keys -> exactly one owner
        if (k0 >= k1) {
          ++p0; k0 = (p0 < M1) ? mk_key(v_s[l0 + p0], i_s[l0 + p0]) : 0ull;
        } else {
          ++p1; k1 = (p1 < M1) ? mk_key(v_s[l1 + p1], i_s[l1 + p1]) : 0ull;
        }
      }
    }
  }
  __syncthreads();
  // --- fp64 re-score of 64 candidates (identical arithmetic to validated) ---
  double myv = -1e300; int myt = 0x7fffffff;
  if (threadIdx.x < NCAND) {
    myt = ct_s[threadIdx.x];
    double s = 0.0;
#pragma unroll
    for (int g = 0; g < 3; ++g) {
      const double* qp = q + ((((size_t)g * NB) + b) * NC + c) * 4;
      const float4 pv = *reinterpret_cast<const float4*>(
          ps + ((((size_t)g * NT) + myt) * NC + c) * 4);
      double pp0 = pv.x, pp1 = pv.y, pp2 = pv.z, pp3 = pv.w;
      double ss = pp0 * pp0 + pp1 * pp1 + pp2 * pp2 + pp3 * pp3;
      double dot = qp[0] * pp0 + qp[1] * pp1 + qp[2] * pp2 + qp[3] * pp3;
      s += dot / fmax(sqrt(ss), 1e-12);
    }
    myv = s * (1.0 / 3.0);
    rv_s[threadIdx.x] = myv;
  }
  __syncthreads();
  // --- rank by counting (v desc, t asc); ranks unique since t unique ---
  int rank = -1;
  if (threadIdx.x < NCAND) {
    rank = 0;
    for (int j = 0; j < NCAND; ++j) {
      double vj = rv_s[j]; int tj = ct_s[j];
      rank += (vj > myv) || (vj == myv && tj < myt);
    }
    if (rank == 0) m0_s = myv;
  }
  __syncthreads();
  if (rank >= 0 && rank < TOPM) { e_s[rank] = exp((myv - m0_s) * 10.0); ts_s[rank] = myt; }
  __syncthreads();
  if (threadIdx.x == 0) {
    double sum = 0.0;
#pragma unroll
    for (int m = 0; m < TOPM; ++m) sum += e_s[m];
    inv_s = 1.0 / sum;
  }
  __syncthreads();
  if (threadIdx.x < TOPM) w_s[threadIdx.x] = (float)(e_s[threadIdx.x] * inv_s);
  __syncthreads();
  // --- coalesced gather: lane p reads 20 contiguous 192B runs of yT16 ---
  const int p = threadIdx.x;
  if (p < NP) {
    const __half* yc = yt16 + (size_t)c * NT * NP + p;
    float acc = 0.f;
#pragma unroll
    for (int m = 0; m < TOPM; ++m)
      acc += w_s[m] * __half2float(yc[(size_t)ts_s[m] * NP]);
    out[(((size_t)b * NP) + p) * NC + c] = acc;
  }
}

// ---------------------------------------------------------------------------
// Fallback (small ws): round-1-proven all-fp64 inline path.
// ---------------------------------------------------------------------------
__global__ __launch_bounds__(256) void sim_topk_inline_kernel(
    const float* __restrict__ ps, const double* __restrict__ q,
    double* __restrict__ cval, int* __restrict__ cidx, int nch, int chunk) {
  const int wav = threadIdx.x >> 6;
  const int c = threadIdx.x & 63;
  const int b = blockIdx.y * 4 + wav;
  const int ch = blockIdx.x;
  double qv[3][4];
#pragma unroll
  for (int g = 0; g < 3; ++g) {
    const double* qp = q + ((((size_t)g * NB) + b) * NC + c) * 4;
    qv[g][0] = qp[0]; qv[g][1] = qp[1]; qv[g][2] = qp[2]; qv[g][3] = qp[3];
  }
  double val[TOPM]; int idx[TOPM];
#pragma unroll
  for (int m = 0; m < TOPM; ++m) { val[m] = -1e300; idx[m] = 0; }
  int t0 = ch * chunk;
  int t1 = t0 + chunk; if (t1 > NT) t1 = NT;
  for (int t = t0; t < t1; ++t) {
    double s = 0.0;
#pragma unroll
    for (int g = 0; g < 3; ++g) {
      const float4 pv = *reinterpret_cast<const float4*>(
          ps + ((((size_t)g * NT) + t) * NC + c) * 4);
      double p0 = pv.x, p1 = pv.y, p2 = pv.z, p3 = pv.w;
      double ss = p0 * p0 + p1 * p1 + p2 * p2 + p3 * p3;
      double dot = qv[g][0] * p0 + qv[g][1] * p1 + qv[g][2] * p2 + qv[g][3] * p3;
      s += dot / fmax(sqrt(ss), 1e-12);
    }
    s *= (1.0 / 3.0);
    if (s > val[TOPM - 1]) {
      double cv = s; int ci = t;
#pragma unroll
      for (int m = 0; m < TOPM; ++m) {
        bool sw = cv > val[m];
        double tv = sw ? val[m] : cv; int ti = sw ? idx[m] : ci;
        val[m] = sw ? cv : val[m];    idx[m] = sw ? ci : idx[m];
        cv = tv; ci = ti;
      }
    }
  }
  double* vout = cval + ((((size_t)b * NC) + c) * nch + ch) * TOPM;
  int* iout = cidx + ((((size_t)b * NC) + c) * nch + ch) * TOPM;
#pragma unroll
  for (int m = 0; m < TOPM; ++m) { vout[m] = val[m]; iout[m] = idx[m]; }
}

__global__ __launch_bounds__(128) void merge_gather_old_kernel(
    const double* __restrict__ cval, const int* __restrict__ cidx,
    const float* __restrict__ y, float* __restrict__ out, int nch) {
  const int c = blockIdx.x;
  const int b = blockIdx.y;
  __shared__ float w_s[TOPM];
  __shared__ int i_s[TOPM];
  if (threadIdx.x == 0) {
    double val[TOPM]; int idx[TOPM];
#pragma unroll
    for (int m = 0; m < TOPM; ++m) { val[m] = -1e300; idx[m] = 0; }
    const double* vin = cval + (((size_t)b * NC) + c) * nch * TOPM;
    const int* iin = cidx + (((size_t)b * NC) + c) * nch * TOPM;
    for (int k = 0; k < nch; ++k) {
      const int base = k * TOPM;
      for (int m = 0; m < TOPM; ++m) {
        double s = vin[base + m];
        if (!(s > val[TOPM - 1])) break;
        double cv = s; int ci = iin[base + m];
#pragma unroll
        for (int mm = 0; mm < TOPM; ++mm) {
          bool sw = cv > val[mm];
          double tv = sw ? val[mm] : cv; int ti = sw ? idx[mm] : ci;
          val[mm] = sw ? cv : val[mm];   idx[mm] = sw ? ci : idx[mm];
          cv = tv; ci = ti;
        }
      }
    }
    double mx = val[0];
    double e[TOPM]; double sum = 0.0;
#pragma unroll
    for (int m = 0; m < TOPM; ++m) { e[m] = exp((val[m] - mx) * 10.0); sum += e[m]; }
    double inv = 1.0 / sum;
#pragma unroll
    for (int m = 0; m < TOPM; ++m) { w_s[m] = (float)(e[m] * inv); i_s[m] = idx[m]; }
  }
  __syncthreads();
  const int p = threadIdx.x;
  if (p < NP) {
    float acc = 0.f;
#pragma unroll
    for (int m = 0; m < TOPM; ++m)
      acc += w_s[m] * y[(((size_t)i_s[m]) * NP + p) * NC + c];
    out[(((size_t)b * NP) + p) * NC + c] = acc;
  }
}

extern "C" void kernel_launch(void* const* d_in, const int* in_sizes, int n_in,
                              void* d_out, int out_size, void* d_ws, size_t ws_size,
                              hipStream_t stream) {
  const float* x = (const float*)d_in[0];
  const float* ps = (const float*)d_in[1];
  const float* y = (const float*)d_in[2];
  float* out = (float*)d_out;
  char* ws = (char*)d_ws;

  const size_t qbytes = (size_t)NG * NB * NC * 4 * sizeof(double);        // 196,608
  const size_t phatbytes = (size_t)NG * NT * NC * 4 * sizeof(float);      // 30.72 MB
  const size_t cvalbytes = (size_t)NB * NC * NCH * M1 * sizeof(float);    // 16.78 MB
  const size_t cidxbytes = (size_t)NB * NC * NCH * M1 * sizeof(int);      // 16.78 MB
  const size_t ytbytes = (size_t)NC * NT * NP * sizeof(__half);           // 122.88 MB

  double* qbuf = (double*)ws;

  if (ws_size >= qbytes + phatbytes + cvalbytes + cidxbytes + ytbytes) {
    float* phat = (float*)(ws + qbytes);
    float* cval = (float*)(ws + qbytes + phatbytes);
    int* cidx = (int*)((char*)cval + cvalbytes);
    __half* yt16 = (__half*)((char*)cidx + cidxbytes);
    prep_kernel<<<dim3(NB + PNBLK + TRBLK), dim3(512), 0, stream>>>(
        x, ps, y, qbuf, phat, yt16);
    sim32_kernel<<<dim3(NB / 16, NCH), dim3(1024), 0, stream>>>(phat, qbuf, cval, cidx);
    merge_gather_kernel<<<dim3(NC, NB), dim3(128), 0, stream>>>(cval, cidx, ps, qbuf,
                                                                yt16, out);
  } else {
    // fallback: round-1-proven all-fp64 path (prep runs qstat class only)
    prep_kernel<<<dim3(NB), dim3(512), 0, stream>>>(x, ps, y, qbuf,
                                                    (float*)nullptr, (__half*)nullptr);
    const size_t per_ch = (size_t)NB * NC * TOPM * (sizeof(double) + sizeof(int));
    int nch = 1;
    if (ws_size > qbytes) {
      size_t mc = (ws_size - qbytes) / per_ch;
      nch = mc < 32 ? (int)mc : 32;
      if (nch < 1) nch = 1;
    }
    const int chunk = (NT + nch - 1) / nch;
    double* cval = (double*)(ws + qbytes);
    int* cidx = (int*)((char*)cval + (size_t)NB * NC * nch * TOPM * sizeof(double));
    sim_topk_inline_kernel<<<dim3(nch, NB / 4), dim3(256), 0, stream>>>(
        ps, qbuf, cval, cidx, nch, chunk);
    merge_gather_old_kernel<<<dim3(NC, NB), dim3(128), 0, stream>>>(cval, cidx, y, out, nch);
  }
}

// Round 10
// 177.676 us; speedup vs baseline: 1.2465x; 1.2465x over previous
//
#include <hip/hip_runtime.h>
#include <hip/hip_fp16.h>
#include <math.h>

#define NB 32
#define NL 512
#define NC 64
#define NG 3
#define NT 10000
#define NP 96
#define TOPM 20
#define M1 8      // per-lane per-chunk fp32 prefilter list
#define NCH 256   // t-chunks (250 real, 6 empty)
#define CHUNK 40
#define QK 16     // extracted per quarter (4 quarters -> 64 candidates)
#define NCAND 64
#define PNBLK 1250   // pnorm blocks (NT*NC/512)
#define TTILE 4      // t rows per transpose block
#define TRBLK (NT / TTILE)  // 2500 transpose blocks (full-row, all 64 c)
#define HSTR 394     // LDS per-c stride in halves (788B ≡ 20 dwords mod 32)
#define GSTR ((size_t)NT * NC * 4)  // float stride between g-planes

// ---------------------------------------------------------------------------
// Kernel 1 (prep, 3 classes): [0,NB) qstat | [NB,NB+PNBLK) pnorm32 |
// [NB+PNBLK,..) y-transpose to fp16 yT[c][t][p].
// Transpose blocks now read FULL 24KB y-rows (all 64 c) -> perfectly
// sequential 98KB stream per block (R9 fix: no more quarter-density reads).
// ---------------------------------------------------------------------------
__global__ __launch_bounds__(512) void prep_kernel(
    const float* __restrict__ x, const float* __restrict__ ps,
    const float* __restrict__ y, double* __restrict__ q,
    float* __restrict__ phat, __half* __restrict__ yt16) {
  __shared__ __align__(16) char smem[NC * HSTR * 2];  // 50,432 B
  if (blockIdx.x < NB) {
    // ---- qstat (R5-R9-proven math) ----
    double* s_sum = (double*)smem;        // [w][g][c] : w*192+g*64+c
    double* s_sq = s_sum + 1536;
    double* s_abs = s_sq + 1536;
    double* s_first = s_abs + 1536;       // [g][c]
    double* s_last = s_first + 192;
    const int b = blockIdx.x, w = threadIdx.x >> 6, c = threadIdx.x & 63;
    const float* xp = x + (size_t)b * NL * NC + c;
    const int l0 = w * 64;
    double sum[3] = {0, 0, 0}, sumsq[3] = {0, 0, 0}, sumabs[3] = {0, 0, 0};
    double prev[3] = {0, 0, 0}, first[3] = {0, 0, 0};
    if (w > 0) {
      double e0 = xp[(l0 - 4) * NC], e1 = xp[(l0 - 3) * NC];
      double e2 = xp[(l0 - 2) * NC], e3 = xp[(l0 - 1) * NC];
      prev[2] = e3; prev[1] = (e2 + e3) * 0.5; prev[0] = (e0 + e1 + e2 + e3) * 0.25;
    }
    double acc2 = 0.0, acc4 = 0.0;
    for (int i = 0; i < 64; ++i) {
      const int l = l0 + i;
      double v = (double)xp[l * NC];
      sum[2] += v; sumsq[2] += v * v;
      if (l == 0) first[2] = v; else sumabs[2] += fabs(v - prev[2]);
      prev[2] = v;
      acc2 += v;
      if (l & 1) {
        double cur = acc2 * 0.5; acc2 = 0.0;
        sum[1] += cur; sumsq[1] += cur * cur;
        if (l == 1) first[1] = cur; else sumabs[1] += fabs(cur - prev[1]);
        prev[1] = cur;
      }
      acc4 += v;
      if ((l & 3) == 3) {
        double cur = acc4 * 0.25; acc4 = 0.0;
        sum[0] += cur; sumsq[0] += cur * cur;
        if (l == 3) first[0] = cur; else sumabs[0] += fabs(cur - prev[0]);
        prev[0] = cur;
      }
    }
    for (int g = 0; g < 3; ++g) {
      s_sum[w * 192 + g * 64 + c] = sum[g];
      s_sq[w * 192 + g * 64 + c] = sumsq[g];
      s_abs[w * 192 + g * 64 + c] = sumabs[g];
    }
    if (w == 0) { for (int g = 0; g < 3; ++g) s_first[g * 64 + c] = first[g]; }
    if (w == 7) { for (int g = 0; g < 3; ++g) s_last[g * 64 + c] = prev[g]; }
    __syncthreads();
    if (w == 0) {
      const double J[3] = {128.0, 256.0, 512.0};
      for (int g = 0; g < 3; ++g) {
        double S = 0, Q2 = 0, A = 0;
        for (int ww = 0; ww < 8; ++ww) {
          S += s_sum[ww * 192 + g * 64 + c];
          Q2 += s_sq[ww * 192 + g * 64 + c];
          A += s_abs[ww * 192 + g * 64 + c];
        }
        double mean = S / J[g];
        double var = Q2 / J[g] - mean * mean; if (var < 0.0) var = 0.0;
        double last = s_last[g * 64 + c];
        double s0 = mean - last;
        double s1 = sqrt(var);
        double s2 = (last - s_first[g * 64 + c]) * (1.0 / 511.0);
        double s3 = A * (1.0 / 511.0);
        double n = sqrt(s0 * s0 + s1 * s1 + s2 * s2 + s3 * s3);
        double inv = 1.0 / fmax(n, 1e-12);
        double* qp = q + ((((size_t)g * NB) + b) * NC + c) * 4;
        qp[0] = s0 * inv; qp[1] = s1 * inv; qp[2] = s2 * inv; qp[3] = s3 * inv;
      }
    }
  } else if (blockIdx.x < NB + PNBLK) {
    // ---- pnorm32 (R6-proven) ----
    const int i = (blockIdx.x - NB) * 512 + threadIdx.x;  // over T*C
    if (i < NT * NC) {
      const int t = i >> 6, c = i & 63;
#pragma unroll
      for (int g = 0; g < 3; ++g) {
        const size_t off = ((((size_t)g * NT) + t) * NC + c) * 4;
        const float4 pv = *reinterpret_cast<const float4*>(ps + off);
        double p0 = pv.x, p1 = pv.y, p2 = pv.z, p3 = pv.w;
        double inv = 1.0 / fmax(sqrt(p0 * p0 + p1 * p1 + p2 * p2 + p3 * p3), 1e-12);
        float4 o;
        o.x = (float)(p0 * inv); o.y = (float)(p1 * inv);
        o.z = (float)(p2 * inv); o.w = (float)(p3 * inv);
        *reinterpret_cast<float4*>(phat + off) = o;
      }
    }
  } else {
    // ---- y transpose: yT16[c][t][p] = fp16(y[t][p][c]), full 64-c blocks ----
    __half2* l2 = reinterpret_cast<__half2*>(smem);  // [c][HSTR/2=197 half2]
    const int tb = blockIdx.x - NB - PNBLK;
    const int T0 = tb * TTILE;
    // stage-in: i = cq(16) x p2(48) x t(4) = 3072; wave reads 2KB contiguous
    for (int i = threadIdx.x; i < 3072; i += 512) {
      const int cq = i & 15;
      const int p2 = (i >> 4) % 48;
      const int t = i / 768;
      const float* rowp = y + ((size_t)(T0 + t) * NP + p2 * 2) * NC + cq * 4;
      const float4 vA = *reinterpret_cast<const float4*>(rowp);
      const float4 vB = *reinterpret_cast<const float4*>(rowp + NC);
      const int base2 = (cq * 4) * 197 + t * 49 + p2;
      l2[base2          ] = __halves2half2(__float2half_rn(vA.x), __float2half_rn(vB.x));
      l2[base2 + 197    ] = __halves2half2(__float2half_rn(vA.y), __float2half_rn(vB.y));
      l2[base2 + 2 * 197] = __halves2half2(__float2half_rn(vA.z), __float2half_rn(vB.z));
      l2[base2 + 3 * 197] = __halves2half2(__float2half_rn(vA.w), __float2half_rn(vB.w));
    }
    __syncthreads();
    // stage-out: j = p2(48) x t(4) x c(64) = 12288; per (c,t) 192B contiguous
    for (int j = threadIdx.x; j < 12288; j += 512) {
      const int p2 = j % 48, t = (j / 48) & 3, c = j / 192;
      const __half2 h = l2[c * 197 + t * 49 + p2];
      *reinterpret_cast<__half2*>(
          yt16 + ((size_t)c * NT + T0 + t) * NP + p2 * 2) = h;
    }
  }
}

__device__ __forceinline__ void insert8(float s, int ti, float val[M1], int idx[M1]) {
  float cv = s; int ci = ti;
#pragma unroll
  for (int m = 0; m < M1; ++m) {
    bool sw = cv > val[m];
    float tv = sw ? val[m] : cv; int tx = sw ? idx[m] : ci;
    val[m] = sw ? cv : val[m];   idx[m] = sw ? ci : idx[m];
    cv = tv; ci = tx;
  }
}

// ---------------------------------------------------------------------------
// Kernel 2: fp32 prefilter scan (R6-proven verbatim). 1024-thr blocks = 16
// waves = 16 b's sharing one chunk stream; grid (2, NCH); LB(1024,8).
// ---------------------------------------------------------------------------
__global__ __launch_bounds__(1024, 8) void sim32_kernel(
    const float* __restrict__ phat, const double* __restrict__ q,
    float* __restrict__ cval, int* __restrict__ cidx) {
  const int wav = threadIdx.x >> 6;
  const int c = threadIdx.x & 63;
  const int b = blockIdx.x * 16 + wav;
  const int ch = blockIdx.y;
  float qv[12];
#pragma unroll
  for (int g = 0; g < 3; ++g) {
    const double* qp = q + ((((size_t)g * NB) + b) * NC + c) * 4;
#pragma unroll
    for (int j = 0; j < 4; ++j) qv[g * 4 + j] = (float)(qp[j] * (1.0 / 3.0));
  }
  float val[M1]; int idx[M1];
#pragma unroll
  for (int m = 0; m < M1; ++m) { val[m] = -1e30f; idx[m] = 0; }
  int t0 = ch * CHUNK;
  int t1 = t0 + CHUNK; if (t1 > NT) t1 = NT;
  for (int t = t0; t + 1 < t1; t += 2) {
    const size_t oA = ((size_t)t * NC + c) * 4;
    const size_t oB = oA + (size_t)NC * 4;
    const float4 a0 = *reinterpret_cast<const float4*>(phat + oA);
    const float4 a1 = *reinterpret_cast<const float4*>(phat + GSTR + oA);
    const float4 a2 = *reinterpret_cast<const float4*>(phat + 2 * GSTR + oA);
    const float4 b0 = *reinterpret_cast<const float4*>(phat + oB);
    const float4 b1 = *reinterpret_cast<const float4*>(phat + GSTR + oB);
    const float4 b2 = *reinterpret_cast<const float4*>(phat + 2 * GSTR + oB);
    float sA = qv[0] * a0.x + qv[1] * a0.y + qv[2] * a0.z + qv[3] * a0.w +
               qv[4] * a1.x + qv[5] * a1.y + qv[6] * a1.z + qv[7] * a1.w +
               qv[8] * a2.x + qv[9] * a2.y + qv[10] * a2.z + qv[11] * a2.w;
    float sB = qv[0] * b0.x + qv[1] * b0.y + qv[2] * b0.z + qv[3] * b0.w +
               qv[4] * b1.x + qv[5] * b1.y + qv[6] * b1.z + qv[7] * b1.w +
               qv[8] * b2.x + qv[9] * b2.y + qv[10] * b2.z + qv[11] * b2.w;
    if (sA > val[M1 - 1]) insert8(sA, t, val, idx);
    if (sB > val[M1 - 1]) insert8(sB, t + 1, val, idx);
  }
  float* vo = cval + ((((size_t)b * NC) + c) * NCH + ch) * M1;
  int* io = cidx + ((((size_t)b * NC) + c) * NCH + ch) * M1;
#pragma unroll
  for (int m = 0; m < M1; ++m) { vo[m] = val[m]; io[m] = idx[m]; }
}

// order-preserving fp32 -> u32 map; key = (v asc-map << 32) | (MAX - t)
// so u64-descending == (v desc, t asc). t unique per row => unique keys.
__device__ __forceinline__ unsigned long long mk_key(float v, int t) {
  unsigned u = __float_as_uint(v);
  u = (u & 0x80000000u) ? ~u : (u | 0x80000000u);
  return ((unsigned long long)u << 32) | (unsigned long long)(0xFFFFFFFFu - (unsigned)t);
}

// ---------------------------------------------------------------------------
// Kernel 3: merge + fp64 rerank (validated arithmetic) + softmax + COALESCED
// fp16 gather from yT16. Block = (c,b), 128 threads. (R8/R9-proven.)
// ---------------------------------------------------------------------------
__global__ __launch_bounds__(128) void merge_gather_kernel(
    const float* __restrict__ cval, const int* __restrict__ cidx,
    const float* __restrict__ ps, const double* __restrict__ q,
    const __half* __restrict__ yt16, float* __restrict__ out) {
  const int c = blockIdx.x, b = blockIdx.y;
  __shared__ float v_s[NCH * M1];
  __shared__ int i_s[NCH * M1];
  __shared__ int ct_s[NCAND];
  __shared__ double rv_s[NCAND];
  __shared__ double m0_s, inv_s;
  __shared__ double e_s[TOPM];
  __shared__ int ts_s[TOPM];
  __shared__ float w_s[TOPM];
  const int n = NCH * M1;  // 2048
  const size_t row = (size_t)b * NC + c;
  const float4* vin = reinterpret_cast<const float4*>(cval + row * n);
  const int4* iin = reinterpret_cast<const int4*>(cidx + row * n);
  for (int k = threadIdx.x; k < n / 4; k += 128) {
    *reinterpret_cast<float4*>(&v_s[k * 4]) = vin[k];
    *reinterpret_cast<int4*>(&i_s[k * 4]) = iin[k];
  }
  __syncthreads();
  // --- quarter extraction: all 128 threads; quarter = (w<<1)|(lane>>5) ---
  {
    const int w = threadIdx.x >> 6, lane = threadIdx.x & 63;
    const int lane32 = lane & 31;
    const int qtr = (w << 1) | (lane >> 5);
    const int l0 = (qtr * 64 + lane32 * 2) * M1;
    const int l1 = l0 + M1;
    int p0 = 0, p1 = 0;
    unsigned long long k0 = mk_key(v_s[l0], i_s[l0]);
    unsigned long long k1 = mk_key(v_s[l1], i_s[l1]);
    for (int r = 0; r < QK; ++r) {
      unsigned long long me = k0 > k1 ? k0 : k1;
      unsigned long long km = me;
#pragma unroll
      for (int st = 1; st < 32; st <<= 1) {
        unsigned long long k2 = __shfl_xor(km, st);
        km = k2 > km ? k2 : km;
      }
      if (lane32 == r)
        ct_s[qtr * QK + r] = (int)(0xFFFFFFFFu - (unsigned)(km & 0xFFFFFFFFull));
      if (me == km) {  // unique keys -> exactly one owner
        if (k0 >= k1) {
          ++p0; k0 = (p0 < M1) ? mk_key(v_s[l0 + p0], i_s[l0 + p0]) : 0ull;
        } else {
          ++p1; k1 = (p1 < M1) ? mk_key(v_s[l1 + p1], i_s[l1 + p1]) : 0ull;
        }
      }
    }
  }
  __syncthreads();
  // --- fp64 re-score of 64 candidates (identical arithmetic to validated) ---
  double myv = -1e300; int myt = 0x7fffffff;
  if (threadIdx.x < NCAND) {
    myt = ct_s[threadIdx.x];
    double s = 0.0;
#pragma unroll
    for (int g = 0; g < 3; ++g) {
      const double* qp = q + ((((size_t)g * NB) + b) * NC + c) * 4;
      const float4 pv = *reinterpret_cast<const float4*>(
          ps + ((((size_t)g * NT) + myt) * NC + c) * 4);
      double pp0 = pv.x, pp1 = pv.y, pp2 = pv.z, pp3 = pv.w;
      double ss = pp0 * pp0 + pp1 * pp1 + pp2 * pp2 + pp3 * pp3;
      double dot = qp[0] * pp0 + qp[1] * pp1 + qp[2] * pp2 + qp[3] * pp3;
      s += dot / fmax(sqrt(ss), 1e-12);
    }
    myv = s * (1.0 / 3.0);
    rv_s[threadIdx.x] = myv;
  }
  __syncthreads();
  // --- rank by counting (v desc, t asc); ranks unique since t unique ---
  int rank = -1;
  if (threadIdx.x < NCAND) {
    rank = 0;
    for (int j = 0; j < NCAND; ++j) {
      double vj = rv_s[j]; int tj = ct_s[j];
      rank += (vj > myv) || (vj == myv && tj < myt);
    }
    if (rank == 0) m0_s = myv;
  }
  __syncthreads();
  if (rank >= 0 && rank < TOPM) { e_s[rank] = exp((myv - m0_s) * 10.0); ts_s[rank] = myt; }
  __syncthreads();
  if (threadIdx.x == 0) {
    double sum = 0.0;
#pragma unroll
    for (int m = 0; m < TOPM; ++m) sum += e_s[m];
    inv_s = 1.0 / sum;
  }
  __syncthreads();
  if (threadIdx.x < TOPM) w_s[threadIdx.x] = (float)(e_s[threadIdx.x] * inv_s);
  __syncthreads();
  // --- coalesced gather: lane p reads 20 contiguous 192B runs of yT16 ---
  const int p = threadIdx.x;
  if (p < NP) {
    const __half* yc = yt16 + (size_t)c * NT * NP + p;
    float acc = 0.f;
#pragma unroll
    for (int m = 0; m < TOPM; ++m)
      acc += w_s[m] * __half2float(yc[(size_t)ts_s[m] * NP]);
    out[(((size_t)b * NP) + p) * NC + c] = acc;
  }
}

// ---------------------------------------------------------------------------
// Fallback (small ws): round-1-proven all-fp64 inline path.
// ---------------------------------------------------------------------------
__global__ __launch_bounds__(256) void sim_topk_inline_kernel(
    const float* __restrict__ ps, const double* __restrict__ q,
    double* __restrict__ cval, int* __restrict__ cidx, int nch, int chunk) {
  const int wav = threadIdx.x >> 6;
  const int c = threadIdx.x & 63;
  const int b = blockIdx.y * 4 + wav;
  const int ch = blockIdx.x;
  double qv[3][4];
#pragma unroll
  for (int g = 0; g < 3; ++g) {
    const double* qp = q + ((((size_t)g * NB) + b) * NC + c) * 4;
    qv[g][0] = qp[0]; qv[g][1] = qp[1]; qv[g][2] = qp[2]; qv[g][3] = qp[3];
  }
  double val[TOPM]; int idx[TOPM];
#pragma unroll
  for (int m = 0; m < TOPM; ++m) { val[m] = -1e300; idx[m] = 0; }
  int t0 = ch * chunk;
  int t1 = t0 + chunk; if (t1 > NT) t1 = NT;
  for (int t = t0; t < t1; ++t) {
    double s = 0.0;
#pragma unroll
    for (int g = 0; g < 3; ++g) {
      const float4 pv = *reinterpret_cast<const float4*>(
          ps + ((((size_t)g * NT) + t) * NC + c) * 4);
      double p0 = pv.x, p1 = pv.y, p2 = pv.z, p3 = pv.w;
      double ss = p0 * p0 + p1 * p1 + p2 * p2 + p3 * p3;
      double dot = qv[g][0] * p0 + qv[g][1] * p1 + qv[g][2] * p2 + qv[g][3] * p3;
      s += dot / fmax(sqrt(ss), 1e-12);
    }
    s *= (1.0 / 3.0);
    if (s > val[TOPM - 1]) {
      double cv = s; int ci = t;
#pragma unroll
      for (int m = 0; m < TOPM; ++m) {
        bool sw = cv > val[m];
        double tv = sw ? val[m] : cv; int ti = sw ? idx[m] : ci;
        val[m] = sw ? cv : val[m];    idx[m] = sw ? ci : idx[m];
        cv = tv; ci = ti;
      }
    }
  }
  double* vout = cval + ((((size_t)b * NC) + c) * nch + ch) * TOPM;
  int* iout = cidx + ((((size_t)b * NC) + c) * nch + ch) * TOPM;
#pragma unroll
  for (int m = 0; m < TOPM; ++m) { vout[m] = val[m]; iout[m] = idx[m]; }
}

__global__ __launch_bounds__(128) void merge_gather_old_kernel(
    const double* __restrict__ cval, const int* __restrict__ cidx,
    const float* __restrict__ y, float* __restrict__ out, int nch) {
  const int c = blockIdx.x;
  const int b = blockIdx.y;
  __shared__ float w_s[TOPM];
  __shared__ int i_s[TOPM];
  if (threadIdx.x == 0) {
    double val[TOPM]; int idx[TOPM];
#pragma unroll
    for (int m = 0; m < TOPM; ++m) { val[m] = -1e300; idx[m] = 0; }
    const double* vin = cval + (((size_t)b * NC) + c) * nch * TOPM;
    const int* iin = cidx + (((size_t)b * NC) + c) * nch * TOPM;
    for (int k = 0; k < nch; ++k) {
      const int base = k * TOPM;
      for (int m = 0; m < TOPM; ++m) {
        double s = vin[base + m];
        if (!(s > val[TOPM - 1])) break;
        double cv = s; int ci = iin[base + m];
#pragma unroll
        for (int mm = 0; mm < TOPM; ++mm) {
          bool sw = cv > val[mm];
          double tv = sw ? val[mm] : cv; int ti = sw ? idx[mm] : ci;
          val[mm] = sw ? cv : val[mm];   idx[mm] = sw ? ci : idx[mm];
          cv = tv; ci = ti;
        }
      }
    }
    double mx = val[0];
    double e[TOPM]; double sum = 0.0;
#pragma unroll
    for (int m = 0; m < TOPM; ++m) { e[m] = exp((val[m] - mx) * 10.0); sum += e[m]; }
    double inv = 1.0 / sum;
#pragma unroll
    for (int m = 0; m < TOPM; ++m) { w_s[m] = (float)(e[m] * inv); i_s[m] = idx[m]; }
  }
  __syncthreads();
  const int p = threadIdx.x;
  if (p < NP) {
    float acc = 0.f;
#pragma unroll
    for (int m = 0; m < TOPM; ++m)
      acc += w_s[m] * y[(((size_t)i_s[m]) * NP + p) * NC + c];
    out[(((size_t)b * NP) + p) * NC + c] = acc;
  }
}

extern "C" void kernel_launch(void* const* d_in, const int* in_sizes, int n_in,
                              void* d_out, int out_size, void* d_ws, size_t ws_size,
                              hipStream_t stream) {
  const float* x = (const float*)d_in[0];
  const float* ps = (const float*)d_in[1];
  const float* y = (const float*)d_in[2];
  float* out = (float*)d_out;
  char* ws = (char*)d_ws;

  const size_t qbytes = (size_t)NG * NB * NC * 4 * sizeof(double);        // 196,608
  const size_t phatbytes = (size_t)NG * NT * NC * 4 * sizeof(float);      // 30.72 MB
  const size_t cvalbytes = (size_t)NB * NC * NCH * M1 * sizeof(float);    // 16.78 MB
  const size_t cidxbytes = (size_t)NB * NC * NCH * M1 * sizeof(int);      // 16.78 MB
  const size_t ytbytes = (size_t)NC * NT * NP * sizeof(__half);           // 122.88 MB

  double* qbuf = (double*)ws;

  if (ws_size >= qbytes + phatbytes + cvalbytes + cidxbytes + ytbytes) {
    float* phat = (float*)(ws + qbytes);
    float* cval = (float*)(ws + qbytes + phatbytes);
    int* cidx = (int*)((char*)cval + cvalbytes);
    __half* yt16 = (__half*)((char*)cidx + cidxbytes);
    prep_kernel<<<dim3(NB + PNBLK + TRBLK), dim3(512), 0, stream>>>(
        x, ps, y, qbuf, phat, yt16);
    sim32_kernel<<<dim3(NB / 16, NCH), dim3(1024), 0, stream>>>(phat, qbuf, cval, cidx);
    merge_gather_kernel<<<dim3(NC, NB), dim3(128), 0, stream>>>(cval, cidx, ps, qbuf,
                                                                yt16, out);
  } else {
    // fallback: round-1-proven all-fp64 path (prep runs qstat class only)
    prep_kernel<<<dim3(NB), dim3(512), 0, stream>>>(x, ps, y, qbuf,
                                                    (float*)nullptr, (__half*)nullptr);
    const size_t per_ch = (size_t)NB * NC * TOPM * (sizeof(double) + sizeof(int));
    int nch = 1;
    if (ws_size > qbytes) {
      size_t mc = (ws_size - qbytes) / per_ch;
      nch = mc < 32 ? (int)mc : 32;
      if (nch < 1) nch = 1;
    }
    const int chunk = (NT + nch - 1) / nch;
    double* cval = (double*)(ws + qbytes);
    int* cidx = (int*)((char*)cval + (size_t)NB * NC * nch * TOPM * sizeof(double));
    sim_topk_inline_kernel<<<dim3(nch, NB / 4), dim3(256), 0, stream>>>(
        ps, qbuf, cval, cidx, nch, chunk);
    merge_gather_old_kernel<<<dim3(NC, NB), dim3(128), 0, stream>>>(cval, cidx, y, out, nch);
  }
}

// Round 11
// 152.954 us; speedup vs baseline: 1.4480x; 1.1616x over previous
//
#include <hip/hip_runtime.h>
#include <math.h>

#define NB 32
#define NL 512
#define NC 64
#define NG 3
#define NT 10000
#define NP 96
#define TOPM 20
#define M1 8      // per-lane per-chunk fp32 prefilter list
#define NCH 256   // t-chunks (250 real, 6 empty)
#define CHUNK 40
#define QK 16     // extracted per quarter (4 quarters -> 64 candidates)
#define NCAND 64
#define PNBLK 1250   // pnorm blocks (NT*NC/512)
#define NENT (NB * NC * TOPM)  // 40960 selected entries
#define GSTR ((size_t)NT * NC * 4)  // float stride between g-planes

// ---------------------------------------------------------------------------
// Kernel 1 (pre, R6-proven): blocks [0,NB) = qstat (8 waves over L-segments,
// LDS combine); blocks [NB,..) = pnorm32.
// ---------------------------------------------------------------------------
__global__ __launch_bounds__(512) void pre_kernel(const float* __restrict__ x,
                                                  const float* __restrict__ ps,
                                                  double* __restrict__ q,
                                                  float* __restrict__ phat) {
  __shared__ double s_sum[8][3][64], s_sq[8][3][64], s_abs[8][3][64];
  __shared__ double s_first[3][64], s_last[3][64];
  if (blockIdx.x < NB) {
    const int b = blockIdx.x, w = threadIdx.x >> 6, c = threadIdx.x & 63;
    const float* xp = x + (size_t)b * NL * NC + c;
    const int l0 = w * 64;
    double sum[3] = {0, 0, 0}, sumsq[3] = {0, 0, 0}, sumabs[3] = {0, 0, 0};
    double prev[3] = {0, 0, 0}, first[3] = {0, 0, 0};
    if (w > 0) {
      double e0 = xp[(l0 - 4) * NC], e1 = xp[(l0 - 3) * NC];
      double e2 = xp[(l0 - 2) * NC], e3 = xp[(l0 - 1) * NC];
      prev[2] = e3; prev[1] = (e2 + e3) * 0.5; prev[0] = (e0 + e1 + e2 + e3) * 0.25;
    }
    double acc2 = 0.0, acc4 = 0.0;
    for (int i = 0; i < 64; ++i) {
      const int l = l0 + i;
      double v = (double)xp[l * NC];
      sum[2] += v; sumsq[2] += v * v;
      if (l == 0) first[2] = v; else sumabs[2] += fabs(v - prev[2]);
      prev[2] = v;
      acc2 += v;
      if (l & 1) {
        double cur = acc2 * 0.5; acc2 = 0.0;
        sum[1] += cur; sumsq[1] += cur * cur;
        if (l == 1) first[1] = cur; else sumabs[1] += fabs(cur - prev[1]);
        prev[1] = cur;
      }
      acc4 += v;
      if ((l & 3) == 3) {
        double cur = acc4 * 0.25; acc4 = 0.0;
        sum[0] += cur; sumsq[0] += cur * cur;
        if (l == 3) first[0] = cur; else sumabs[0] += fabs(cur - prev[0]);
        prev[0] = cur;
      }
    }
    for (int g = 0; g < 3; ++g) {
      s_sum[w][g][c] = sum[g]; s_sq[w][g][c] = sumsq[g]; s_abs[w][g][c] = sumabs[g];
    }
    if (w == 0) { for (int g = 0; g < 3; ++g) s_first[g][c] = first[g]; }
    if (w == 7) { for (int g = 0; g < 3; ++g) s_last[g][c] = prev[g]; }
    __syncthreads();
    if (w == 0) {
      const double J[3] = {128.0, 256.0, 512.0};
      for (int g = 0; g < 3; ++g) {
        double S = 0, Q2 = 0, A = 0;
        for (int ww = 0; ww < 8; ++ww) {
          S += s_sum[ww][g][c]; Q2 += s_sq[ww][g][c]; A += s_abs[ww][g][c];
        }
        double mean = S / J[g];
        double var = Q2 / J[g] - mean * mean; if (var < 0.0) var = 0.0;
        double last = s_last[g][c];
        double s0 = mean - last;
        double s1 = sqrt(var);
        double s2 = (last - s_first[g][c]) * (1.0 / 511.0);
        double s3 = A * (1.0 / 511.0);
        double n = sqrt(s0 * s0 + s1 * s1 + s2 * s2 + s3 * s3);
        double inv = 1.0 / fmax(n, 1e-12);
        double* qp = q + ((((size_t)g * NB) + b) * NC + c) * 4;
        qp[0] = s0 * inv; qp[1] = s1 * inv; qp[2] = s2 * inv; qp[3] = s3 * inv;
      }
    }
  } else {
    const int i = (blockIdx.x - NB) * 512 + threadIdx.x;  // over T*C
    if (i < NT * NC) {
      const int t = i >> 6, c = i & 63;
#pragma unroll
      for (int g = 0; g < 3; ++g) {
        const size_t off = ((((size_t)g * NT) + t) * NC + c) * 4;
        const float4 pv = *reinterpret_cast<const float4*>(ps + off);
        double p0 = pv.x, p1 = pv.y, p2 = pv.z, p3 = pv.w;
        double inv = 1.0 / fmax(sqrt(p0 * p0 + p1 * p1 + p2 * p2 + p3 * p3), 1e-12);
        float4 o;
        o.x = (float)(p0 * inv); o.y = (float)(p1 * inv);
        o.z = (float)(p2 * inv); o.w = (float)(p3 * inv);
        *reinterpret_cast<float4*>(phat + off) = o;
      }
    }
  }
}

__device__ __forceinline__ void insert8(float s, int ti, float val[M1], int idx[M1]) {
  float cv = s; int ci = ti;
#pragma unroll
  for (int m = 0; m < M1; ++m) {
    bool sw = cv > val[m];
    float tv = sw ? val[m] : cv; int tx = sw ? idx[m] : ci;
    val[m] = sw ? cv : val[m];   idx[m] = sw ? ci : idx[m];
    cv = tv; ci = tx;
  }
}

// ---------------------------------------------------------------------------
// Kernel 2 (R6-proven + fused hist zeroing): fp32 prefilter scan. 1024-thr
// blocks = 16 waves = 16 b's sharing one chunk stream; grid (2, NCH).
// Blocks (0, y<10) also zero the 10000-entry t-histogram (stream order
// guarantees completion before merge_rerank's atomics).
// ---------------------------------------------------------------------------
__global__ __launch_bounds__(1024, 8) void sim32_kernel(
    const float* __restrict__ phat, const double* __restrict__ q,
    float* __restrict__ cval, int* __restrict__ cidx, int* __restrict__ hist) {
  if (blockIdx.x == 0 && blockIdx.y < 10) {
    const int idx = blockIdx.y * 1024 + threadIdx.x;
    if (idx < NT) hist[idx] = 0;
  }
  const int wav = threadIdx.x >> 6;
  const int c = threadIdx.x & 63;
  const int b = blockIdx.x * 16 + wav;
  const int ch = blockIdx.y;
  float qv[12];
#pragma unroll
  for (int g = 0; g < 3; ++g) {
    const double* qp = q + ((((size_t)g * NB) + b) * NC + c) * 4;
#pragma unroll
    for (int j = 0; j < 4; ++j) qv[g * 4 + j] = (float)(qp[j] * (1.0 / 3.0));
  }
  float val[M1]; int idx[M1];
#pragma unroll
  for (int m = 0; m < M1; ++m) { val[m] = -1e30f; idx[m] = 0; }
  int t0 = ch * CHUNK;
  int t1 = t0 + CHUNK; if (t1 > NT) t1 = NT;
  for (int t = t0; t + 1 < t1; t += 2) {
    const size_t oA = ((size_t)t * NC + c) * 4;
    const size_t oB = oA + (size_t)NC * 4;
    const float4 a0 = *reinterpret_cast<const float4*>(phat + oA);
    const float4 a1 = *reinterpret_cast<const float4*>(phat + GSTR + oA);
    const float4 a2 = *reinterpret_cast<const float4*>(phat + 2 * GSTR + oA);
    const float4 b0 = *reinterpret_cast<const float4*>(phat + oB);
    const float4 b1 = *reinterpret_cast<const float4*>(phat + GSTR + oB);
    const float4 b2 = *reinterpret_cast<const float4*>(phat + 2 * GSTR + oB);
    float sA = qv[0] * a0.x + qv[1] * a0.y + qv[2] * a0.z + qv[3] * a0.w +
               qv[4] * a1.x + qv[5] * a1.y + qv[6] * a1.z + qv[7] * a1.w +
               qv[8] * a2.x + qv[9] * a2.y + qv[10] * a2.z + qv[11] * a2.w;
    float sB = qv[0] * b0.x + qv[1] * b0.y + qv[2] * b0.z + qv[3] * b0.w +
               qv[4] * b1.x + qv[5] * b1.y + qv[6] * b1.z + qv[7] * b1.w +
               qv[8] * b2.x + qv[9] * b2.y + qv[10] * b2.z + qv[11] * b2.w;
    if (sA > val[M1 - 1]) insert8(sA, t, val, idx);
    if (sB > val[M1 - 1]) insert8(sB, t + 1, val, idx);
  }
  float* vo = cval + ((((size_t)b * NC) + c) * NCH + ch) * M1;
  int* io = cidx + ((((size_t)b * NC) + c) * NCH + ch) * M1;
#pragma unroll
  for (int m = 0; m < M1; ++m) { vo[m] = val[m]; io[m] = idx[m]; }
}

// order-preserving fp32 -> u32 map; key = (v asc-map << 32) | (MAX - t)
// so u64-descending == (v desc, t asc). t unique per row => unique keys.
__device__ __forceinline__ unsigned long long mk_key(float v, int t) {
  unsigned u = __float_as_uint(v);
  u = (u & 0x80000000u) ? ~u : (u | 0x80000000u);
  return ((unsigned long long)u << 32) | (unsigned long long)(0xFFFFFFFFu - (unsigned)t);
}

// ---------------------------------------------------------------------------
// Kernel 3: merge + fp64 rerank (validated arithmetic) + softmax -> writes
// (w, t)[20] per row + t-histogram atomics. Block = (c,b), 128 threads.
// Extraction/rank/softmax identical to R6-proven merge_gather.
// ---------------------------------------------------------------------------
__global__ __launch_bounds__(128) void merge_rerank_kernel(
    const float* __restrict__ cval, const int* __restrict__ cidx,
    const float* __restrict__ ps, const double* __restrict__ q,
    float* __restrict__ w_out, int* __restrict__ t_out, int* __restrict__ hist) {
  const int c = blockIdx.x, b = blockIdx.y;
  __shared__ float v_s[NCH * M1];
  __shared__ int i_s[NCH * M1];
  __shared__ int ct_s[NCAND];
  __shared__ double rv_s[NCAND];
  __shared__ double m0_s, inv_s;
  __shared__ double e_s[TOPM];
  __shared__ int ts_s[TOPM];
  const int n = NCH * M1;  // 2048
  const size_t row = (size_t)b * NC + c;
  const float4* vin = reinterpret_cast<const float4*>(cval + row * n);
  const int4* iin = reinterpret_cast<const int4*>(cidx + row * n);
  for (int k = threadIdx.x; k < n / 4; k += 128) {
    *reinterpret_cast<float4*>(&v_s[k * 4]) = vin[k];
    *reinterpret_cast<int4*>(&i_s[k * 4]) = iin[k];
  }
  __syncthreads();
  // --- quarter extraction: all 128 threads; quarter = (w<<1)|(lane>>5) ---
  {
    const int w = threadIdx.x >> 6, lane = threadIdx.x & 63;
    const int lane32 = lane & 31;
    const int qtr = (w << 1) | (lane >> 5);
    const int l0 = (qtr * 64 + lane32 * 2) * M1;
    const int l1 = l0 + M1;
    int p0 = 0, p1 = 0;
    unsigned long long k0 = mk_key(v_s[l0], i_s[l0]);
    unsigned long long k1 = mk_key(v_s[l1], i_s[l1]);
    for (int r = 0; r < QK; ++r) {
      unsigned long long me = k0 > k1 ? k0 : k1;
      unsigned long long km = me;
#pragma unroll
      for (int st = 1; st < 32; st <<= 1) {
        unsigned long long k2 = __shfl_xor(km, st);
        km = k2 > km ? k2 : km;
      }
      if (lane32 == r)
        ct_s[qtr * QK + r] = (int)(0xFFFFFFFFu - (unsigned)(km & 0xFFFFFFFFull));
      if (me == km) {  // unique keys -> exactly one owner
        if (k0 >= k1) {
          ++p0; k0 = (p0 < M1) ? mk_key(v_s[l0 + p0], i_s[l0 + p0]) : 0ull;
        } else {
          ++p1; k1 = (p1 < M1) ? mk_key(v_s[l1 + p1], i_s[l1 + p1]) : 0ull;
        }
      }
    }
  }
  __syncthreads();
  // --- fp64 re-score of 64 candidates (identical arithmetic to validated) ---
  double myv = -1e300; int myt = 0x7fffffff;
  if (threadIdx.x < NCAND) {
    myt = ct_s[threadIdx.x];
    double s = 0.0;
#pragma unroll
    for (int g = 0; g < 3; ++g) {
      const double* qp = q + ((((size_t)g * NB) + b) * NC + c) * 4;
      const float4 pv = *reinterpret_cast<const float4*>(
          ps + ((((size_t)g * NT) + myt) * NC + c) * 4);
      double pp0 = pv.x, pp1 = pv.y, pp2 = pv.z, pp3 = pv.w;
      double ss = pp0 * pp0 + pp1 * pp1 + pp2 * pp2 + pp3 * pp3;
      double dot = qp[0] * pp0 + qp[1] * pp1 + qp[2] * pp2 + qp[3] * pp3;
      s += dot / fmax(sqrt(ss), 1e-12);
    }
    myv = s * (1.0 / 3.0);
    rv_s[threadIdx.x] = myv;
  }
  __syncthreads();
  // --- rank by counting (v desc, t asc); ranks unique since t unique ---
  int rank = -1;
  if (threadIdx.x < NCAND) {
    rank = 0;
    for (int j = 0; j < NCAND; ++j) {
      double vj = rv_s[j]; int tj = ct_s[j];
      rank += (vj > myv) || (vj == myv && tj < myt);
    }
    if (rank == 0) m0_s = myv;
  }
  __syncthreads();
  if (rank >= 0 && rank < TOPM) { e_s[rank] = exp((myv - m0_s) * 10.0); ts_s[rank] = myt; }
  __syncthreads();
  if (threadIdx.x == 0) {
    double sum = 0.0;
#pragma unroll
    for (int m = 0; m < TOPM; ++m) sum += e_s[m];
    inv_s = 1.0 / sum;
  }
  __syncthreads();
  if (threadIdx.x < TOPM) {
    const int t = ts_s[threadIdx.x];
    w_out[row * TOPM + threadIdx.x] = (float)(e_s[threadIdx.x] * inv_s);
    t_out[row * TOPM + threadIdx.x] = t;
    atomicAdd(&hist[t], 1);
  }
}

// ---------------------------------------------------------------------------
// Kernel 4: exclusive scan of hist[10000] -> bin_off[10001], cursor copy.
// Single block, 1024 threads x 10 elements, Hillis-Steele over partials.
// ---------------------------------------------------------------------------
__global__ __launch_bounds__(1024) void scan_kernel(const int* __restrict__ hist,
                                                    int* __restrict__ bin_off,
                                                    int* __restrict__ cursor) {
  __shared__ int part[1024];
  const int tid = threadIdx.x;
  int loc[10];
  int s = 0;
#pragma unroll
  for (int j = 0; j < 10; ++j) {
    const int idx = tid * 10 + j;
    const int v = (idx < NT) ? hist[idx] : 0;
    loc[j] = s;
    s += v;
  }
  part[tid] = s;
  __syncthreads();
  for (int st = 1; st < 1024; st <<= 1) {
    const int v = (tid >= st) ? part[tid - st] : 0;
    __syncthreads();
    part[tid] += v;
    __syncthreads();
  }
  const int base = (tid == 0) ? 0 : part[tid - 1];
#pragma unroll
  for (int j = 0; j < 10; ++j) {
    const int idx = tid * 10 + j;
    if (idx < NT) {
      const int off = base + loc[j];
      bin_off[idx] = off;
      cursor[idx] = off;
    }
  }
  if (tid == 1023) bin_off[NT] = part[1023];
}

// ---------------------------------------------------------------------------
// Kernel 5: scatter entry ids into t-bins (atomic cursor; bin order is
// arbitrary but each entry owns its own partial slot -> deterministic output).
// ---------------------------------------------------------------------------
__global__ __launch_bounds__(256) void scatter_kernel(
    const int* __restrict__ t_out, int* __restrict__ cursor,
    int* __restrict__ bin_slot) {
  const int i = blockIdx.x * 256 + threadIdx.x;
  if (i < NENT) {
    const int t = t_out[i];
    const int pos = atomicAdd(&cursor[t], 1);
    bin_slot[pos] = i;
  }
}

// ---------------------------------------------------------------------------
// Kernel 6: one block per t. Stage y[t] (24KB, CONTIGUOUS read) into LDS
// (65-float c-stride: bank (p+c)%32, 2-way = free), then serve each user
// entry: partial[i][p] = w_i * y[t][p][c_i]. Coalesced 384B writes.
// ---------------------------------------------------------------------------
__global__ __launch_bounds__(128) void process_kernel(
    const float* __restrict__ y, const int* __restrict__ bin_off,
    const int* __restrict__ bin_slot, const float* __restrict__ w_out,
    float* __restrict__ partial) {
  const int t = blockIdx.x;
  const int start = bin_off[t];
  const int k = bin_off[t + 1] - start;
  if (k == 0) return;
  __shared__ float lds[NP * 65];
  const float4* yrow = reinterpret_cast<const float4*>(y + (size_t)t * NP * NC);
#pragma unroll
  for (int r = 0; r < 12; ++r) {
    const int e4 = threadIdx.x + r * 128;
    const float4 v = yrow[e4];
    const int p = e4 >> 4;
    const int c = (e4 & 15) * 4;
    lds[p * 65 + c] = v.x; lds[p * 65 + c + 1] = v.y;
    lds[p * 65 + c + 2] = v.z; lds[p * 65 + c + 3] = v.w;
  }
  __syncthreads();
  const int p = threadIdx.x;
  for (int e = 0; e < k; ++e) {
    const int i = bin_slot[start + e];
    const float w = w_out[i];
    const int c = (i / TOPM) & 63;
    if (p < NP) partial[(size_t)i * NP + p] = w * lds[p * 65 + c];
  }
}

// ---------------------------------------------------------------------------
// Kernel 7: out[b][p][c] = sum_m partial[row*20+m][p], fixed m order.
// ---------------------------------------------------------------------------
__global__ __launch_bounds__(128) void final_kernel(const float* __restrict__ partial,
                                                    float* __restrict__ out) {
  const int row = blockIdx.x;
  const int p = threadIdx.x;
  if (p >= NP) return;
  const int b = row >> 6, c = row & 63;
  const float* pp = partial + (size_t)row * TOPM * NP + p;
  float acc = 0.f;
#pragma unroll
  for (int m = 0; m < TOPM; ++m) acc += pp[m * NP];
  out[(((size_t)b * NP) + p) * NC + c] = acc;
}

// ---------------------------------------------------------------------------
// Fallback (small ws): round-1-proven all-fp64 inline path.
// ---------------------------------------------------------------------------
__global__ __launch_bounds__(256) void sim_topk_inline_kernel(
    const float* __restrict__ ps, const double* __restrict__ q,
    double* __restrict__ cval, int* __restrict__ cidx, int nch, int chunk) {
  const int wav = threadIdx.x >> 6;
  const int c = threadIdx.x & 63;
  const int b = blockIdx.y * 4 + wav;
  const int ch = blockIdx.x;
  double qv[3][4];
#pragma unroll
  for (int g = 0; g < 3; ++g) {
    const double* qp = q + ((((size_t)g * NB) + b) * NC + c) * 4;
    qv[g][0] = qp[0]; qv[g][1] = qp[1]; qv[g][2] = qp[2]; qv[g][3] = qp[3];
  }
  double val[TOPM]; int idx[TOPM];
#pragma unroll
  for (int m = 0; m < TOPM; ++m) { val[m] = -1e300; idx[m] = 0; }
  int t0 = ch * chunk;
  int t1 = t0 + chunk; if (t1 > NT) t1 = NT;
  for (int t = t0; t < t1; ++t) {
    double s = 0.0;
#pragma unroll
    for (int g = 0; g < 3; ++g) {
      const float4 pv = *reinterpret_cast<const float4*>(
          ps + ((((size_t)g * NT) + t) * NC + c) * 4);
      double p0 = pv.x, p1 = pv.y, p2 = pv.z, p3 = pv.w;
      double ss = p0 * p0 + p1 * p1 + p2 * p2 + p3 * p3;
      double dot = qv[g][0] * p0 + qv[g][1] * p1 + qv[g][2] * p2 + qv[g][3] * p3;
      s += dot / fmax(sqrt(ss), 1e-12);
    }
    s *= (1.0 / 3.0);
    if (s > val[TOPM - 1]) {
      double cv = s; int ci = t;
#pragma unroll
      for (int m = 0; m < TOPM; ++m) {
        bool sw = cv > val[m];
        double tv = sw ? val[m] : cv; int ti = sw ? idx[m] : ci;
        val[m] = sw ? cv : val[m];    idx[m] = sw ? ci : idx[m];
        cv = tv; ci = ti;
      }
    }
  }
  double* vout = cval + ((((size_t)b * NC) + c) * nch + ch) * TOPM;
  int* iout = cidx + ((((size_t)b * NC) + c) * nch + ch) * TOPM;
#pragma unroll
  for (int m = 0; m < TOPM; ++m) { vout[m] = val[m]; iout[m] = idx[m]; }
}

__global__ __launch_bounds__(128) void merge_gather_old_kernel(
    const double* __restrict__ cval, const int* __restrict__ cidx,
    const float* __restrict__ y, float* __restrict__ out, int nch) {
  const int c = blockIdx.x;
  const int b = blockIdx.y;
  __shared__ float w_s[TOPM];
  __shared__ int i_s[TOPM];
  if (threadIdx.x == 0) {
    double val[TOPM]; int idx[TOPM];
#pragma unroll
    for (int m = 0; m < TOPM; ++m) { val[m] = -1e300; idx[m] = 0; }
    const double* vin = cval + (((size_t)b * NC) + c) * nch * TOPM;
    const int* iin = cidx + (((size_t)b * NC) + c) * nch * TOPM;
    for (int k = 0; k < nch; ++k) {
      const int base = k * TOPM;
      for (int m = 0; m < TOPM; ++m) {
        double s = vin[base + m];
        if (!(s > val[TOPM - 1])) break;
        double cv = s; int ci = iin[base + m];
#pragma unroll
        for (int mm = 0; mm < TOPM; ++mm) {
          bool sw = cv > val[mm];
          double tv = sw ? val[mm] : cv; int ti = sw ? idx[mm] : ci;
          val[mm] = sw ? cv : val[mm];   idx[mm] = sw ? ci : idx[mm];
          cv = tv; ci = ti;
        }
      }
    }
    double mx = val[0];
    double e[TOPM]; double sum = 0.0;
#pragma unroll
    for (int m = 0; m < TOPM; ++m) { e[m] = exp((val[m] - mx) * 10.0); sum += e[m]; }
    double inv = 1.0 / sum;
#pragma unroll
    for (int m = 0; m < TOPM; ++m) { w_s[m] = (float)(e[m] * inv); i_s[m] = idx[m]; }
  }
  __syncthreads();
  const int p = threadIdx.x;
  if (p < NP) {
    float acc = 0.f;
#pragma unroll
    for (int m = 0; m < TOPM; ++m)
      acc += w_s[m] * y[(((size_t)i_s[m]) * NP + p) * NC + c];
    out[(((size_t)b * NP) + p) * NC + c] = acc;
  }
}

extern "C" void kernel_launch(void* const* d_in, const int* in_sizes, int n_in,
                              void* d_out, int out_size, void* d_ws, size_t ws_size,
                              hipStream_t stream) {
  const float* x = (const float*)d_in[0];
  const float* ps = (const float*)d_in[1];
  const float* y = (const float*)d_in[2];
  float* out = (float*)d_out;
  char* ws = (char*)d_ws;

  const size_t qbytes = (size_t)NG * NB * NC * 4 * sizeof(double);        // 196,608
  const size_t phatbytes = (size_t)NG * NT * NC * 4 * sizeof(float);      // 30.72 MB
  const size_t cvalbytes = (size_t)NB * NC * NCH * M1 * sizeof(float);    // 16.78 MB
  const size_t cidxbytes = cvalbytes;                                     // 16.78 MB
  const size_t wtbytes = (size_t)NENT * sizeof(float);                    // 163,840
  const size_t histbytes = (size_t)NT * sizeof(int);                      // 40,000
  const size_t offbytes = (size_t)(NT + 4) * sizeof(int);                 // 40,016
  const size_t slotbytes = (size_t)NENT * sizeof(int);                    // 163,840
  const size_t partbytes = (size_t)NENT * NP * sizeof(float);             // 15.73 MB

  double* qbuf = (double*)ws;
  size_t off = qbytes;
  float* phat = (float*)(ws + off); off += phatbytes;
  float* cval = (float*)(ws + off); off += cvalbytes;
  int* cidx = (int*)(ws + off); off += cidxbytes;
  float* w_out = (float*)(ws + off); off += wtbytes;
  int* t_out = (int*)(ws + off); off += wtbytes;
  int* hist = (int*)(ws + off); off += histbytes;
  int* bin_off = (int*)(ws + off); off += offbytes;
  int* cursor = (int*)(ws + off); off += histbytes;
  int* bin_slot = (int*)(ws + off); off += slotbytes;
  float* partial = (float*)(ws + off); off += partbytes;

  if (ws_size >= off) {
    pre_kernel<<<dim3(NB + PNBLK), dim3(512), 0, stream>>>(x, ps, qbuf, phat);
    sim32_kernel<<<dim3(NB / 16, NCH), dim3(1024), 0, stream>>>(phat, qbuf, cval,
                                                                cidx, hist);
    merge_rerank_kernel<<<dim3(NC, NB), dim3(128), 0, stream>>>(
        cval, cidx, ps, qbuf, w_out, t_out, hist);
    scan_kernel<<<dim3(1), dim3(1024), 0, stream>>>(hist, bin_off, cursor);
    scatter_kernel<<<dim3((NENT + 255) / 256), dim3(256), 0, stream>>>(
        t_out, cursor, bin_slot);
    process_kernel<<<dim3(NT), dim3(128), 0, stream>>>(y, bin_off, bin_slot,
                                                       w_out, partial);
    final_kernel<<<dim3(NB * NC), dim3(128), 0, stream>>>(partial, out);
  } else {
    // fallback: round-1-proven all-fp64 path (pre runs qstat class only)
    pre_kernel<<<dim3(NB), dim3(512), 0, stream>>>(x, ps, qbuf, (float*)nullptr);
    const size_t per_ch = (size_t)NB * NC * TOPM * (sizeof(double) + sizeof(int));
    int nch = 1;
    if (ws_size > qbytes) {
      size_t mc = (ws_size - qbytes) / per_ch;
      nch = mc < 32 ? (int)mc : 32;
      if (nch < 1) nch = 1;
    }
    const int chunk = (NT + nch - 1) / nch;
    double* fcval = (double*)(ws + qbytes);
    int* fcidx = (int*)((char*)fcval + (size_t)NB * NC * nch * TOPM * sizeof(double));
    sim_topk_inline_kernel<<<dim3(nch, NB / 4), dim3(256), 0, stream>>>(
        ps, qbuf, fcval, fcidx, nch, chunk);
    merge_gather_old_kernel<<<dim3(NC, NB), dim3(128), 0, stream>>>(fcval, fcidx, y,
                                                                    out, nch);
  }
}

// Round 12
// 152.798 us; speedup vs baseline: 1.4494x; 1.0010x over previous
//
#include <hip/hip_runtime.h>
#include <math.h>

#define NB 32
#define NL 512
#define NC 64
#define NG 3
#define NT 10000
#define NP 96
#define TOPM 20
#define M1 8      // per-lane per-chunk fp32 prefilter list
#define NCH 256   // t-chunks (250 real, 6 empty)
#define CHUNK 40
#define QK 16     // extracted per quarter (4 quarters -> 64 candidates)
#define NCAND 64
#define PNBLK 1250   // pnorm blocks (NT*NC/512)
#define NENT (NB * NC * TOPM)  // 40960 selected entries
#define PBATCH 128   // bin entries staged per round in process_kernel
#define GSTR ((size_t)NT * NC * 4)  // float stride between g-planes

// ---------------------------------------------------------------------------
// Kernel 1 (pre, R6-proven): blocks [0,NB) = qstat (8 waves over L-segments,
// LDS combine); blocks [NB,..) = pnorm32.
// ---------------------------------------------------------------------------
__global__ __launch_bounds__(512) void pre_kernel(const float* __restrict__ x,
                                                  const float* __restrict__ ps,
                                                  double* __restrict__ q,
                                                  float* __restrict__ phat) {
  __shared__ double s_sum[8][3][64], s_sq[8][3][64], s_abs[8][3][64];
  __shared__ double s_first[3][64], s_last[3][64];
  if (blockIdx.x < NB) {
    const int b = blockIdx.x, w = threadIdx.x >> 6, c = threadIdx.x & 63;
    const float* xp = x + (size_t)b * NL * NC + c;
    const int l0 = w * 64;
    double sum[3] = {0, 0, 0}, sumsq[3] = {0, 0, 0}, sumabs[3] = {0, 0, 0};
    double prev[3] = {0, 0, 0}, first[3] = {0, 0, 0};
    if (w > 0) {
      double e0 = xp[(l0 - 4) * NC], e1 = xp[(l0 - 3) * NC];
      double e2 = xp[(l0 - 2) * NC], e3 = xp[(l0 - 1) * NC];
      prev[2] = e3; prev[1] = (e2 + e3) * 0.5; prev[0] = (e0 + e1 + e2 + e3) * 0.25;
    }
    double acc2 = 0.0, acc4 = 0.0;
    for (int i = 0; i < 64; ++i) {
      const int l = l0 + i;
      double v = (double)xp[l * NC];
      sum[2] += v; sumsq[2] += v * v;
      if (l == 0) first[2] = v; else sumabs[2] += fabs(v - prev[2]);
      prev[2] = v;
      acc2 += v;
      if (l & 1) {
        double cur = acc2 * 0.5; acc2 = 0.0;
        sum[1] += cur; sumsq[1] += cur * cur;
        if (l == 1) first[1] = cur; else sumabs[1] += fabs(cur - prev[1]);
        prev[1] = cur;
      }
      acc4 += v;
      if ((l & 3) == 3) {
        double cur = acc4 * 0.25; acc4 = 0.0;
        sum[0] += cur; sumsq[0] += cur * cur;
        if (l == 3) first[0] = cur; else sumabs[0] += fabs(cur - prev[0]);
        prev[0] = cur;
      }
    }
    for (int g = 0; g < 3; ++g) {
      s_sum[w][g][c] = sum[g]; s_sq[w][g][c] = sumsq[g]; s_abs[w][g][c] = sumabs[g];
    }
    if (w == 0) { for (int g = 0; g < 3; ++g) s_first[g][c] = first[g]; }
    if (w == 7) { for (int g = 0; g < 3; ++g) s_last[g][c] = prev[g]; }
    __syncthreads();
    if (w == 0) {
      const double J[3] = {128.0, 256.0, 512.0};
      for (int g = 0; g < 3; ++g) {
        double S = 0, Q2 = 0, A = 0;
        for (int ww = 0; ww < 8; ++ww) {
          S += s_sum[ww][g][c]; Q2 += s_sq[ww][g][c]; A += s_abs[ww][g][c];
        }
        double mean = S / J[g];
        double var = Q2 / J[g] - mean * mean; if (var < 0.0) var = 0.0;
        double last = s_last[g][c];
        double s0 = mean - last;
        double s1 = sqrt(var);
        double s2 = (last - s_first[g][c]) * (1.0 / 511.0);
        double s3 = A * (1.0 / 511.0);
        double n = sqrt(s0 * s0 + s1 * s1 + s2 * s2 + s3 * s3);
        double inv = 1.0 / fmax(n, 1e-12);
        double* qp = q + ((((size_t)g * NB) + b) * NC + c) * 4;
        qp[0] = s0 * inv; qp[1] = s1 * inv; qp[2] = s2 * inv; qp[3] = s3 * inv;
      }
    }
  } else {
    const int i = (blockIdx.x - NB) * 512 + threadIdx.x;  // over T*C
    if (i < NT * NC) {
      const int t = i >> 6, c = i & 63;
#pragma unroll
      for (int g = 0; g < 3; ++g) {
        const size_t off = ((((size_t)g * NT) + t) * NC + c) * 4;
        const float4 pv = *reinterpret_cast<const float4*>(ps + off);
        double p0 = pv.x, p1 = pv.y, p2 = pv.z, p3 = pv.w;
        double inv = 1.0 / fmax(sqrt(p0 * p0 + p1 * p1 + p2 * p2 + p3 * p3), 1e-12);
        float4 o;
        o.x = (float)(p0 * inv); o.y = (float)(p1 * inv);
        o.z = (float)(p2 * inv); o.w = (float)(p3 * inv);
        *reinterpret_cast<float4*>(phat + off) = o;
      }
    }
  }
}

__device__ __forceinline__ void insert8(float s, int ti, float val[M1], int idx[M1]) {
  float cv = s; int ci = ti;
#pragma unroll
  for (int m = 0; m < M1; ++m) {
    bool sw = cv > val[m];
    float tv = sw ? val[m] : cv; int tx = sw ? idx[m] : ci;
    val[m] = sw ? cv : val[m];   idx[m] = sw ? ci : idx[m];
    cv = tv; ci = tx;
  }
}

// ---------------------------------------------------------------------------
// Kernel 2 (R6-proven + fused hist zeroing): fp32 prefilter scan. 1024-thr
// blocks = 16 waves = 16 b's sharing one chunk stream; grid (2, NCH).
// ---------------------------------------------------------------------------
__global__ __launch_bounds__(1024, 8) void sim32_kernel(
    const float* __restrict__ phat, const double* __restrict__ q,
    float* __restrict__ cval, int* __restrict__ cidx, int* __restrict__ hist) {
  if (blockIdx.x == 0 && blockIdx.y < 10) {
    const int idx = blockIdx.y * 1024 + threadIdx.x;
    if (idx < NT) hist[idx] = 0;
  }
  const int wav = threadIdx.x >> 6;
  const int c = threadIdx.x & 63;
  const int b = blockIdx.x * 16 + wav;
  const int ch = blockIdx.y;
  float qv[12];
#pragma unroll
  for (int g = 0; g < 3; ++g) {
    const double* qp = q + ((((size_t)g * NB) + b) * NC + c) * 4;
#pragma unroll
    for (int j = 0; j < 4; ++j) qv[g * 4 + j] = (float)(qp[j] * (1.0 / 3.0));
  }
  float val[M1]; int idx[M1];
#pragma unroll
  for (int m = 0; m < M1; ++m) { val[m] = -1e30f; idx[m] = 0; }
  int t0 = ch * CHUNK;
  int t1 = t0 + CHUNK; if (t1 > NT) t1 = NT;
  for (int t = t0; t + 1 < t1; t += 2) {
    const size_t oA = ((size_t)t * NC + c) * 4;
    const size_t oB = oA + (size_t)NC * 4;
    const float4 a0 = *reinterpret_cast<const float4*>(phat + oA);
    const float4 a1 = *reinterpret_cast<const float4*>(phat + GSTR + oA);
    const float4 a2 = *reinterpret_cast<const float4*>(phat + 2 * GSTR + oA);
    const float4 b0 = *reinterpret_cast<const float4*>(phat + oB);
    const float4 b1 = *reinterpret_cast<const float4*>(phat + GSTR + oB);
    const float4 b2 = *reinterpret_cast<const float4*>(phat + 2 * GSTR + oB);
    float sA = qv[0] * a0.x + qv[1] * a0.y + qv[2] * a0.z + qv[3] * a0.w +
               qv[4] * a1.x + qv[5] * a1.y + qv[6] * a1.z + qv[7] * a1.w +
               qv[8] * a2.x + qv[9] * a2.y + qv[10] * a2.z + qv[11] * a2.w;
    float sB = qv[0] * b0.x + qv[1] * b0.y + qv[2] * b0.z + qv[3] * b0.w +
               qv[4] * b1.x + qv[5] * b1.y + qv[6] * b1.z + qv[7] * b1.w +
               qv[8] * b2.x + qv[9] * b2.y + qv[10] * b2.z + qv[11] * b2.w;
    if (sA > val[M1 - 1]) insert8(sA, t, val, idx);
    if (sB > val[M1 - 1]) insert8(sB, t + 1, val, idx);
  }
  float* vo = cval + ((((size_t)b * NC) + c) * NCH + ch) * M1;
  int* io = cidx + ((((size_t)b * NC) + c) * NCH + ch) * M1;
#pragma unroll
  for (int m = 0; m < M1; ++m) { vo[m] = val[m]; io[m] = idx[m]; }
}

// order-preserving fp32 -> u32 map; key = (v asc-map << 32) | (MAX - t)
// so u64-descending == (v desc, t asc). t unique per row => unique keys.
__device__ __forceinline__ unsigned long long mk_key(float v, int t) {
  unsigned u = __float_as_uint(v);
  u = (u & 0x80000000u) ? ~u : (u | 0x80000000u);
  return ((unsigned long long)u << 32) | (unsigned long long)(0xFFFFFFFFu - (unsigned)t);
}

// ---------------------------------------------------------------------------
// Kernel 3 (R11-proven): merge + fp64 rerank (validated arithmetic) + softmax
// -> (w, t)[20] per row + t-histogram atomics. Block = (c,b), 128 threads.
// ---------------------------------------------------------------------------
__global__ __launch_bounds__(128) void merge_rerank_kernel(
    const float* __restrict__ cval, const int* __restrict__ cidx,
    const float* __restrict__ ps, const double* __restrict__ q,
    float* __restrict__ w_out, int* __restrict__ t_out, int* __restrict__ hist) {
  const int c = blockIdx.x, b = blockIdx.y;
  __shared__ float v_s[NCH * M1];
  __shared__ int i_s[NCH * M1];
  __shared__ int ct_s[NCAND];
  __shared__ double rv_s[NCAND];
  __shared__ double m0_s, inv_s;
  __shared__ double e_s[TOPM];
  __shared__ int ts_s[TOPM];
  const int n = NCH * M1;  // 2048
  const size_t row = (size_t)b * NC + c;
  const float4* vin = reinterpret_cast<const float4*>(cval + row * n);
  const int4* iin = reinterpret_cast<const int4*>(cidx + row * n);
  for (int k = threadIdx.x; k < n / 4; k += 128) {
    *reinterpret_cast<float4*>(&v_s[k * 4]) = vin[k];
    *reinterpret_cast<int4*>(&i_s[k * 4]) = iin[k];
  }
  __syncthreads();
  // --- quarter extraction: all 128 threads; quarter = (w<<1)|(lane>>5) ---
  {
    const int w = threadIdx.x >> 6, lane = threadIdx.x & 63;
    const int lane32 = lane & 31;
    const int qtr = (w << 1) | (lane >> 5);
    const int l0 = (qtr * 64 + lane32 * 2) * M1;
    const int l1 = l0 + M1;
    int p0 = 0, p1 = 0;
    unsigned long long k0 = mk_key(v_s[l0], i_s[l0]);
    unsigned long long k1 = mk_key(v_s[l1], i_s[l1]);
    for (int r = 0; r < QK; ++r) {
      unsigned long long me = k0 > k1 ? k0 : k1;
      unsigned long long km = me;
#pragma unroll
      for (int st = 1; st < 32; st <<= 1) {
        unsigned long long k2 = __shfl_xor(km, st);
        km = k2 > km ? k2 : km;
      }
      if (lane32 == r)
        ct_s[qtr * QK + r] = (int)(0xFFFFFFFFu - (unsigned)(km & 0xFFFFFFFFull));
      if (me == km) {  // unique keys -> exactly one owner
        if (k0 >= k1) {
          ++p0; k0 = (p0 < M1) ? mk_key(v_s[l0 + p0], i_s[l0 + p0]) : 0ull;
        } else {
          ++p1; k1 = (p1 < M1) ? mk_key(v_s[l1 + p1], i_s[l1 + p1]) : 0ull;
        }
      }
    }
  }
  __syncthreads();
  // --- fp64 re-score of 64 candidates (identical arithmetic to validated) ---
  double myv = -1e300; int myt = 0x7fffffff;
  if (threadIdx.x < NCAND) {
    myt = ct_s[threadIdx.x];
    double s = 0.0;
#pragma unroll
    for (int g = 0; g < 3; ++g) {
      const double* qp = q + ((((size_t)g * NB) + b) * NC + c) * 4;
      const float4 pv = *reinterpret_cast<const float4*>(
          ps + ((((size_t)g * NT) + myt) * NC + c) * 4);
      double pp0 = pv.x, pp1 = pv.y, pp2 = pv.z, pp3 = pv.w;
      double ss = pp0 * pp0 + pp1 * pp1 + pp2 * pp2 + pp3 * pp3;
      double dot = qp[0] * pp0 + qp[1] * pp1 + qp[2] * pp2 + qp[3] * pp3;
      s += dot / fmax(sqrt(ss), 1e-12);
    }
    myv = s * (1.0 / 3.0);
    rv_s[threadIdx.x] = myv;
  }
  __syncthreads();
  // --- rank by counting (v desc, t asc); ranks unique since t unique ---
  int rank = -1;
  if (threadIdx.x < NCAND) {
    rank = 0;
    for (int j = 0; j < NCAND; ++j) {
      double vj = rv_s[j]; int tj = ct_s[j];
      rank += (vj > myv) || (vj == myv && tj < myt);
    }
    if (rank == 0) m0_s = myv;
  }
  __syncthreads();
  if (rank >= 0 && rank < TOPM) { e_s[rank] = exp((myv - m0_s) * 10.0); ts_s[rank] = myt; }
  __syncthreads();
  if (threadIdx.x == 0) {
    double sum = 0.0;
#pragma unroll
    for (int m = 0; m < TOPM; ++m) sum += e_s[m];
    inv_s = 1.0 / sum;
  }
  __syncthreads();
  if (threadIdx.x < TOPM) {
    const int t = ts_s[threadIdx.x];
    w_out[row * TOPM + threadIdx.x] = (float)(e_s[threadIdx.x] * inv_s);
    t_out[row * TOPM + threadIdx.x] = t;
    atomicAdd(&hist[t], 1);
  }
}

// ---------------------------------------------------------------------------
// Kernel 4 (R11-proven): exclusive scan of hist -> bin_off[10001] + cursor.
// ---------------------------------------------------------------------------
__global__ __launch_bounds__(1024) void scan_kernel(const int* __restrict__ hist,
                                                    int* __restrict__ bin_off,
                                                    int* __restrict__ cursor) {
  __shared__ int part[1024];
  const int tid = threadIdx.x;
  int loc[10];
  int s = 0;
#pragma unroll
  for (int j = 0; j < 10; ++j) {
    const int idx = tid * 10 + j;
    const int v = (idx < NT) ? hist[idx] : 0;
    loc[j] = s;
    s += v;
  }
  part[tid] = s;
  __syncthreads();
  for (int st = 1; st < 1024; st <<= 1) {
    const int v = (tid >= st) ? part[tid - st] : 0;
    __syncthreads();
    part[tid] += v;
    __syncthreads();
  }
  const int base = (tid == 0) ? 0 : part[tid - 1];
#pragma unroll
  for (int j = 0; j < 10; ++j) {
    const int idx = tid * 10 + j;
    if (idx < NT) {
      const int off = base + loc[j];
      bin_off[idx] = off;
      cursor[idx] = off;
    }
  }
  if (tid == 1023) bin_off[NT] = part[1023];
}

// ---------------------------------------------------------------------------
// Kernel 5 (R11-proven): scatter entry ids into t-bins.
// ---------------------------------------------------------------------------
__global__ __launch_bounds__(256) void scatter_kernel(
    const int* __restrict__ t_out, int* __restrict__ cursor,
    int* __restrict__ bin_slot) {
  const int i = blockIdx.x * 256 + threadIdx.x;
  if (i < NENT) {
    const int t = t_out[i];
    const int pos = atomicAdd(&cursor[t], 1);
    bin_slot[pos] = i;
  }
}

// ---------------------------------------------------------------------------
// Kernel 6 (REWORKED): one block per t, 256 threads (24 waves/CU at 26KB LDS).
// Stage y[t] (24KB contiguous) into LDS; batch-stage bin (slot,w,c) triples
// in ONE parallel round (kills R11's serial dependent-load chain); serve 2
// entries concurrently via thread-halves. partial[i][p] = w_i * y[t][p][c_i].
// ---------------------------------------------------------------------------
__global__ __launch_bounds__(256) void process_kernel(
    const float* __restrict__ y, const int* __restrict__ bin_off,
    const int* __restrict__ bin_slot, const float* __restrict__ w_out,
    float* __restrict__ partial) {
  const int t = blockIdx.x;
  const int start = bin_off[t];
  const int k = bin_off[t + 1] - start;
  if (k == 0) return;
  __shared__ float lds[NP * 65];   // 24,960 B
  __shared__ float w_l[PBATCH];
  __shared__ int i_l[PBATCH];
  __shared__ int c_l[PBATCH];
  const float4* yrow = reinterpret_cast<const float4*>(y + (size_t)t * NP * NC);
#pragma unroll
  for (int r = 0; r < 6; ++r) {
    const int e4 = threadIdx.x + r * 256;
    const float4 v = yrow[e4];
    const int p = e4 >> 4;
    const int c = (e4 & 15) * 4;
    lds[p * 65 + c] = v.x; lds[p * 65 + c + 1] = v.y;
    lds[p * 65 + c + 2] = v.z; lds[p * 65 + c + 3] = v.w;
  }
  for (int base = 0; base < k; base += PBATCH) {
    const int nb = (k - base < PBATCH) ? (k - base) : PBATCH;
    if (threadIdx.x < nb) {
      const int i = bin_slot[start + base + threadIdx.x];
      i_l[threadIdx.x] = i;
      w_l[threadIdx.x] = w_out[i];
      c_l[threadIdx.x] = (i / TOPM) & 63;
    }
    __syncthreads();
    const int h = threadIdx.x >> 7;   // two entry-parallel halves
    const int p = threadIdx.x & 127;
    for (int e = h; e < nb; e += 2) {
      if (p < NP)
        partial[(size_t)i_l[e] * NP + p] = w_l[e] * lds[p * 65 + c_l[e]];
    }
    __syncthreads();
  }
}

// ---------------------------------------------------------------------------
// Kernel 7 (R11-proven): out[b][p][c] = sum_m partial[row*20+m][p].
// ---------------------------------------------------------------------------
__global__ __launch_bounds__(128) void final_kernel(const float* __restrict__ partial,
                                                    float* __restrict__ out) {
  const int row = blockIdx.x;
  const int p = threadIdx.x;
  if (p >= NP) return;
  const int b = row >> 6, c = row & 63;
  const float* pp = partial + (size_t)row * TOPM * NP + p;
  float acc = 0.f;
#pragma unroll
  for (int m = 0; m < TOPM; ++m) acc += pp[m * NP];
  out[(((size_t)b * NP) + p) * NC + c] = acc;
}

// ---------------------------------------------------------------------------
// Fallback (small ws): round-1-proven all-fp64 inline path.
// ---------------------------------------------------------------------------
__global__ __launch_bounds__(256) void sim_topk_inline_kernel(
    const float* __restrict__ ps, const double* __restrict__ q,
    double* __restrict__ cval, int* __restrict__ cidx, int nch, int chunk) {
  const int wav = threadIdx.x >> 6;
  const int c = threadIdx.x & 63;
  const int b = blockIdx.y * 4 + wav;
  const int ch = blockIdx.x;
  double qv[3][4];
#pragma unroll
  for (int g = 0; g < 3; ++g) {
    const double* qp = q + ((((size_t)g * NB) + b) * NC + c) * 4;
    qv[g][0] = qp[0]; qv[g][1] = qp[1]; qv[g][2] = qp[2]; qv[g][3] = qp[3];
  }
  double val[TOPM]; int idx[TOPM];
#pragma unroll
  for (int m = 0; m < TOPM; ++m) { val[m] = -1e300; idx[m] = 0; }
  int t0 = ch * chunk;
  int t1 = t0 + chunk; if (t1 > NT) t1 = NT;
  for (int t = t0; t < t1; ++t) {
    double s = 0.0;
#pragma unroll
    for (int g = 0; g < 3; ++g) {
      const float4 pv = *reinterpret_cast<const float4*>(
          ps + ((((size_t)g * NT) + t) * NC + c) * 4);
      double p0 = pv.x, p1 = pv.y, p2 = pv.z, p3 = pv.w;
      double ss = p0 * p0 + p1 * p1 + p2 * p2 + p3 * p3;
      double dot = qv[g][0] * p0 + qv[g][1] * p1 + qv[g][2] * p2 + qv[g][3] * p3;
      s += dot / fmax(sqrt(ss), 1e-12);
    }
    s *= (1.0 / 3.0);
    if (s > val[TOPM - 1]) {
      double cv = s; int ci = t;
#pragma unroll
      for (int m = 0; m < TOPM; ++m) {
        bool sw = cv > val[m];
        double tv = sw ? val[m] : cv; int ti = sw ? idx[m] : ci;
        val[m] = sw ? cv : val[m];    idx[m] = sw ? ci : idx[m];
        cv = tv; ci = ti;
      }
    }
  }
  double* vout = cval + ((((size_t)b * NC) + c) * nch + ch) * TOPM;
  int* iout = cidx + ((((size_t)b * NC) + c) * nch + ch) * TOPM;
#pragma unroll
  for (int m = 0; m < TOPM; ++m) { vout[m] = val[m]; iout[m] = idx[m]; }
}

__global__ __launch_bounds__(128) void merge_gather_old_kernel(
    const double* __restrict__ cval, const int* __restrict__ cidx,
    const float* __restrict__ y, float* __restrict__ out, int nch) {
  const int c = blockIdx.x;
  const int b = blockIdx.y;
  __shared__ float w_s[TOPM];
  __shared__ int i_s[TOPM];
  if (threadIdx.x == 0) {
    double val[TOPM]; int idx[TOPM];
#pragma unroll
    for (int m = 0; m < TOPM; ++m) { val[m] = -1e300; idx[m] = 0; }
    const double* vin = cval + (((size_t)b * NC) + c) * nch * TOPM;
    const int* iin = cidx + (((size_t)b * NC) + c) * nch * TOPM;
    for (int k = 0; k < nch; ++k) {
      const int base = k * TOPM;
      for (int m = 0; m < TOPM; ++m) {
        double s = vin[base + m];
        if (!(s > val[TOPM - 1])) break;
        double cv = s; int ci = iin[base + m];
#pragma unroll
        for (int mm = 0; mm < TOPM; ++mm) {
          bool sw = cv > val[mm];
          double tv = sw ? val[mm] : cv; int ti = sw ? idx[mm] : ci;
          val[mm] = sw ? cv : val[mm];   idx[mm] = sw ? ci : idx[mm];
          cv = tv; ci = ti;
        }
      }
    }
    double mx = val[0];
    double e[TOPM]; double sum = 0.0;
#pragma unroll
    for (int m = 0; m < TOPM; ++m) { e[m] = exp((val[m] - mx) * 10.0); sum += e[m]; }
    double inv = 1.0 / sum;
#pragma unroll
    for (int m = 0; m < TOPM; ++m) { w_s[m] = (float)(e[m] * inv); i_s[m] = idx[m]; }
  }
  __syncthreads();
  const int p = threadIdx.x;
  if (p < NP) {
    float acc = 0.f;
#pragma unroll
    for (int m = 0; m < TOPM; ++m)
      acc += w_s[m] * y[(((size_t)i_s[m]) * NP + p) * NC + c];
    out[(((size_t)b * NP) + p) * NC + c] = acc;
  }
}

extern "C" void kernel_launch(void* const* d_in, const int* in_sizes, int n_in,
                              void* d_out, int out_size, void* d_ws, size_t ws_size,
                              hipStream_t stream) {
  const float* x = (const float*)d_in[0];
  const float* ps = (const float*)d_in[1];
  const float* y = (const float*)d_in[2];
  float* out = (float*)d_out;
  char* ws = (char*)d_ws;

  const size_t qbytes = (size_t)NG * NB * NC * 4 * sizeof(double);        // 196,608
  const size_t phatbytes = (size_t)NG * NT * NC * 4 * sizeof(float);      // 30.72 MB
  const size_t cvalbytes = (size_t)NB * NC * NCH * M1 * sizeof(float);    // 16.78 MB
  const size_t cidxbytes = cvalbytes;                                     // 16.78 MB
  const size_t wtbytes = (size_t)NENT * sizeof(float);                    // 163,840
  const size_t histbytes = (size_t)NT * sizeof(int);                      // 40,000
  const size_t offbytes = (size_t)(NT + 4) * sizeof(int);                 // 40,016
  const size_t slotbytes = (size_t)NENT * sizeof(int);                    // 163,840
  const size_t partbytes = (size_t)NENT * NP * sizeof(float);             // 15.73 MB

  double* qbuf = (double*)ws;
  size_t off = qbytes;
  float* phat = (float*)(ws + off); off += phatbytes;
  float* cval = (float*)(ws + off); off += cvalbytes;
  int* cidx = (int*)(ws + off); off += cidxbytes;
  float* w_out = (float*)(ws + off); off += wtbytes;
  int* t_out = (int*)(ws + off); off += wtbytes;
  int* hist = (int*)(ws + off); off += histbytes;
  int* bin_off = (int*)(ws + off); off += offbytes;
  int* cursor = (int*)(ws + off); off += histbytes;
  int* bin_slot = (int*)(ws + off); off += slotbytes;
  float* partial = (float*)(ws + off); off += partbytes;

  if (ws_size >= off) {
    pre_kernel<<<dim3(NB + PNBLK), dim3(512), 0, stream>>>(x, ps, qbuf, phat);
    sim32_kernel<<<dim3(NB / 16, NCH), dim3(1024), 0, stream>>>(phat, qbuf, cval,
                                                                cidx, hist);
    merge_rerank_kernel<<<dim3(NC, NB), dim3(128), 0, stream>>>(
        cval, cidx, ps, qbuf, w_out, t_out, hist);
    scan_kernel<<<dim3(1), dim3(1024), 0, stream>>>(hist, bin_off, cursor);
    scatter_kernel<<<dim3((NENT + 255) / 256), dim3(256), 0, stream>>>(
        t_out, cursor, bin_slot);
    process_kernel<<<dim3(NT), dim3(256), 0, stream>>>(y, bin_off, bin_slot,
                                                       w_out, partial);
    final_kernel<<<dim3(NB * NC), dim3(128), 0, stream>>>(partial, out);
  } else {
    // fallback: round-1-proven all-fp64 path (pre runs qstat class only)
    pre_kernel<<<dim3(NB), dim3(512), 0, stream>>>(x, ps, qbuf, (float*)nullptr);
    const size_t per_ch = (size_t)NB * NC * TOPM * (sizeof(double) + sizeof(int));
    int nch = 1;
    if (ws_size > qbytes) {
      size_t mc = (ws_size - qbytes) / per_ch;
      nch = mc < 32 ? (int)mc : 32;
      if (nch < 1) nch = 1;
    }
    const int chunk = (NT + nch - 1) / nch;
    double* fcval = (double*)(ws + qbytes);
    int* fcidx = (int*)((char*)fcval + (size_t)NB * NC * nch * TOPM * sizeof(double));
    sim_topk_inline_kernel<<<dim3(nch, NB / 4), dim3(256), 0, stream>>>(
        ps, qbuf, fcval, fcidx, nch, chunk);
    merge_gather_old_kernel<<<dim3(NC, NB), dim3(128), 0, stream>>>(fcval, fcidx, y,
                                                                    out, nch);
  }
}

// Round 13
// 144.162 us; speedup vs baseline: 1.5363x; 1.0599x over previous
//
#include <hip/hip_runtime.h>
#include <hip/hip_fp16.h>
#include <math.h>

#define NB 32
#define NL 512
#define NC 64
#define NG 3
#define NT 10000
#define NP 96
#define TOPM 20
#define M1 8      // per-lane per-chunk fp32 prefilter list
#define NCH 256   // t-chunks (250 real, 6 empty)
#define CHUNK 40
#define QK 16     // extracted per quarter (4 quarters -> 64 candidates)
#define NCAND 64
#define PNBLK 1250   // pnorm blocks (NT*NC/512)
#define P16STR ((size_t)NT * NC)  // uint2 (8B) stride between g-planes of phat16

union H2U { uint2 u; __half2 h[2]; };

// ---------------------------------------------------------------------------
// Kernel 1 (pre): blocks [0,NB) = qstat (R5-R12-proven math); blocks [NB,..)
// = pnorm -> fp16 phat16[g][t][c][4] (8B per (g,t,c), coalesced 512B stores).
// ---------------------------------------------------------------------------
__global__ __launch_bounds__(512) void pre_kernel(const float* __restrict__ x,
                                                  const float* __restrict__ ps,
                                                  double* __restrict__ q,
                                                  uint2* __restrict__ phat16) {
  __shared__ double s_sum[8][3][64], s_sq[8][3][64], s_abs[8][3][64];
  __shared__ double s_first[3][64], s_last[3][64];
  if (blockIdx.x < NB) {
    const int b = blockIdx.x, w = threadIdx.x >> 6, c = threadIdx.x & 63;
    const float* xp = x + (size_t)b * NL * NC + c;
    const int l0 = w * 64;
    double sum[3] = {0, 0, 0}, sumsq[3] = {0, 0, 0}, sumabs[3] = {0, 0, 0};
    double prev[3] = {0, 0, 0}, first[3] = {0, 0, 0};
    if (w > 0) {
      double e0 = xp[(l0 - 4) * NC], e1 = xp[(l0 - 3) * NC];
      double e2 = xp[(l0 - 2) * NC], e3 = xp[(l0 - 1) * NC];
      prev[2] = e3; prev[1] = (e2 + e3) * 0.5; prev[0] = (e0 + e1 + e2 + e3) * 0.25;
    }
    double acc2 = 0.0, acc4 = 0.0;
    for (int i = 0; i < 64; ++i) {
      const int l = l0 + i;
      double v = (double)xp[l * NC];
      sum[2] += v; sumsq[2] += v * v;
      if (l == 0) first[2] = v; else sumabs[2] += fabs(v - prev[2]);
      prev[2] = v;
      acc2 += v;
      if (l & 1) {
        double cur = acc2 * 0.5; acc2 = 0.0;
        sum[1] += cur; sumsq[1] += cur * cur;
        if (l == 1) first[1] = cur; else sumabs[1] += fabs(cur - prev[1]);
        prev[1] = cur;
      }
      acc4 += v;
      if ((l & 3) == 3) {
        double cur = acc4 * 0.25; acc4 = 0.0;
        sum[0] += cur; sumsq[0] += cur * cur;
        if (l == 3) first[0] = cur; else sumabs[0] += fabs(cur - prev[0]);
        prev[0] = cur;
      }
    }
    for (int g = 0; g < 3; ++g) {
      s_sum[w][g][c] = sum[g]; s_sq[w][g][c] = sumsq[g]; s_abs[w][g][c] = sumabs[g];
    }
    if (w == 0) { for (int g = 0; g < 3; ++g) s_first[g][c] = first[g]; }
    if (w == 7) { for (int g = 0; g < 3; ++g) s_last[g][c] = prev[g]; }
    __syncthreads();
    if (w == 0) {
      const double J[3] = {128.0, 256.0, 512.0};
      for (int g = 0; g < 3; ++g) {
        double S = 0, Q2 = 0, A = 0;
        for (int ww = 0; ww < 8; ++ww) {
          S += s_sum[ww][g][c]; Q2 += s_sq[ww][g][c]; A += s_abs[ww][g][c];
        }
        double mean = S / J[g];
        double var = Q2 / J[g] - mean * mean; if (var < 0.0) var = 0.0;
        double last = s_last[g][c];
        double s0 = mean - last;
        double s1 = sqrt(var);
        double s2 = (last - s_first[g][c]) * (1.0 / 511.0);
        double s3 = A * (1.0 / 511.0);
        double n = sqrt(s0 * s0 + s1 * s1 + s2 * s2 + s3 * s3);
        double inv = 1.0 / fmax(n, 1e-12);
        double* qp = q + ((((size_t)g * NB) + b) * NC + c) * 4;
        qp[0] = s0 * inv; qp[1] = s1 * inv; qp[2] = s2 * inv; qp[3] = s3 * inv;
      }
    }
  } else {
    const int i = (blockIdx.x - NB) * 512 + threadIdx.x;  // over T*C
    if (i < NT * NC) {
#pragma unroll
      for (int g = 0; g < 3; ++g) {
        const size_t off = ((size_t)g * NT * NC + i) * 4;
        const float4 pv = *reinterpret_cast<const float4*>(ps + off);
        double p0 = pv.x, p1 = pv.y, p2 = pv.z, p3 = pv.w;
        double inv = 1.0 / fmax(sqrt(p0 * p0 + p1 * p1 + p2 * p2 + p3 * p3), 1e-12);
        H2U o;
        o.h[0] = __halves2half2(__float2half_rn((float)(p0 * inv)),
                                __float2half_rn((float)(p1 * inv)));
        o.h[1] = __halves2half2(__float2half_rn((float)(p2 * inv)),
                                __float2half_rn((float)(p3 * inv)));
        phat16[(size_t)g * P16STR + i] = o.u;
      }
    }
  }
}

__device__ __forceinline__ void insert8(float s, int ti, float val[M1], int idx[M1]) {
  float cv = s; int ci = ti;
#pragma unroll
  for (int m = 0; m < M1; ++m) {
    bool sw = cv > val[m];
    float tv = sw ? val[m] : cv; int tx = sw ? idx[m] : ci;
    val[m] = sw ? cv : val[m];   idx[m] = sw ? ci : idx[m];
    cv = tv; ci = tx;
  }
}

#if defined(__has_builtin)
#if __has_builtin(__builtin_amdgcn_fdot2)
#define HAVE_FDOT2 1
#endif
#endif

__device__ __forceinline__ float sim_dot(const uint2* __restrict__ p16,
                                         size_t o,
#ifdef HAVE_FDOT2
                                         const __half2 qh[6]
#else
                                         const float qv[12]
#endif
                                         ) {
  H2U a0, a1, a2;
  a0.u = p16[o];
  a1.u = p16[P16STR + o];
  a2.u = p16[2 * P16STR + o];
#ifdef HAVE_FDOT2
  float s = 0.f;
  s = __builtin_amdgcn_fdot2(qh[0], a0.h[0], s, false);
  s = __builtin_amdgcn_fdot2(qh[1], a0.h[1], s, false);
  s = __builtin_amdgcn_fdot2(qh[2], a1.h[0], s, false);
  s = __builtin_amdgcn_fdot2(qh[3], a1.h[1], s, false);
  s = __builtin_amdgcn_fdot2(qh[4], a2.h[0], s, false);
  s = __builtin_amdgcn_fdot2(qh[5], a2.h[1], s, false);
  return s;
#else
  float2 f0 = __half22float2(a0.h[0]), f1 = __half22float2(a0.h[1]);
  float2 f2 = __half22float2(a1.h[0]), f3 = __half22float2(a1.h[1]);
  float2 f4 = __half22float2(a2.h[0]), f5 = __half22float2(a2.h[1]);
  return qv[0] * f0.x + qv[1] * f0.y + qv[2] * f1.x + qv[3] * f1.y +
         qv[4] * f2.x + qv[5] * f2.y + qv[6] * f3.x + qv[7] * f3.y +
         qv[8] * f4.x + qv[9] * f4.y + qv[10] * f5.x + qv[11] * f5.y;
#endif
}

// ---------------------------------------------------------------------------
// Kernel 2: fp16-phat prefilter scan. R6-proven shape: 1024-thr blocks = 16
// waves = 16 b's sharing one chunk stream; grid (2, NCH); LB(1024,8).
// Bytes halved vs fp32 phat (8B/lane/g); dot via v_dot2_f32_f16 if present.
// ---------------------------------------------------------------------------
__global__ __launch_bounds__(1024, 8) void sim32_kernel(
    const uint2* __restrict__ p16, const double* __restrict__ q,
    float* __restrict__ cval, int* __restrict__ cidx) {
  const int wav = threadIdx.x >> 6;
  const int c = threadIdx.x & 63;
  const int b = blockIdx.x * 16 + wav;
  const int ch = blockIdx.y;
#ifdef HAVE_FDOT2
  __half2 qh[6];
#pragma unroll
  for (int g = 0; g < 3; ++g) {
    const double* qp = q + ((((size_t)g * NB) + b) * NC + c) * 4;
    qh[g * 2 + 0] = __halves2half2(__float2half_rn((float)(qp[0] * (1.0 / 3.0))),
                                   __float2half_rn((float)(qp[1] * (1.0 / 3.0))));
    qh[g * 2 + 1] = __halves2half2(__float2half_rn((float)(qp[2] * (1.0 / 3.0))),
                                   __float2half_rn((float)(qp[3] * (1.0 / 3.0))));
  }
#else
  float qv[12];
#pragma unroll
  for (int g = 0; g < 3; ++g) {
    const double* qp = q + ((((size_t)g * NB) + b) * NC + c) * 4;
#pragma unroll
    for (int j = 0; j < 4; ++j) qv[g * 4 + j] = (float)(qp[j] * (1.0 / 3.0));
  }
#endif
  float val[M1]; int idx[M1];
#pragma unroll
  for (int m = 0; m < M1; ++m) { val[m] = -1e30f; idx[m] = 0; }
  int t0 = ch * CHUNK;
  int t1 = t0 + CHUNK; if (t1 > NT) t1 = NT;
  for (int t = t0; t + 1 < t1; t += 2) {
    const size_t oA = (size_t)t * NC + c;
    const size_t oB = oA + NC;
#ifdef HAVE_FDOT2
    float sA = sim_dot(p16, oA, qh);
    float sB = sim_dot(p16, oB, qh);
#else
    float sA = sim_dot(p16, oA, qv);
    float sB = sim_dot(p16, oB, qv);
#endif
    if (sA > val[M1 - 1]) insert8(sA, t, val, idx);
    if (sB > val[M1 - 1]) insert8(sB, t + 1, val, idx);
  }
  float* vo = cval + ((((size_t)b * NC) + c) * NCH + ch) * M1;
  int* io = cidx + ((((size_t)b * NC) + c) * NCH + ch) * M1;
#pragma unroll
  for (int m = 0; m < M1; ++m) { vo[m] = val[m]; io[m] = idx[m]; }
}

// order-preserving fp32 -> u32 map; key = (v asc-map << 32) | (MAX - t)
// so u64-descending == (v desc, t asc). t unique per row => unique keys.
__device__ __forceinline__ unsigned long long mk_key(float v, int t) {
  unsigned u = __float_as_uint(v);
  u = (u & 0x80000000u) ? ~u : (u | 0x80000000u);
  return ((unsigned long long)u << 32) | (unsigned long long)(0xFFFFFFFFu - (unsigned)t);
}

// ---------------------------------------------------------------------------
// Kernel 3 (R6-proven + t-sorted gather): merge + fp64 rerank (validated
// arithmetic, raw ps) + softmax + scattered gather in t-ascending order.
// Block = (c,b), 128 threads.
// ---------------------------------------------------------------------------
__global__ __launch_bounds__(128) void merge_gather_kernel(
    const float* __restrict__ cval, const int* __restrict__ cidx,
    const float* __restrict__ ps, const double* __restrict__ q,
    const float* __restrict__ y, float* __restrict__ out) {
  const int c = blockIdx.x, b = blockIdx.y;
  __shared__ float v_s[NCH * M1];
  __shared__ int i_s[NCH * M1];
  __shared__ int ct_s[NCAND];
  __shared__ double rv_s[NCAND];
  __shared__ double m0_s, inv_s;
  __shared__ double e_s[TOPM];
  __shared__ int ts_s[TOPM];
  __shared__ float w2_s[TOPM];
  __shared__ int t2_s[TOPM];
  const int n = NCH * M1;  // 2048
  const size_t row = (size_t)b * NC + c;
  const float4* vin = reinterpret_cast<const float4*>(cval + row * n);
  const int4* iin = reinterpret_cast<const int4*>(cidx + row * n);
  for (int k = threadIdx.x; k < n / 4; k += 128) {
    *reinterpret_cast<float4*>(&v_s[k * 4]) = vin[k];
    *reinterpret_cast<int4*>(&i_s[k * 4]) = iin[k];
  }
  __syncthreads();
  // --- quarter extraction: all 128 threads; quarter = (w<<1)|(lane>>5) ---
  {
    const int w = threadIdx.x >> 6, lane = threadIdx.x & 63;
    const int lane32 = lane & 31;
    const int qtr = (w << 1) | (lane >> 5);
    const int l0 = (qtr * 64 + lane32 * 2) * M1;
    const int l1 = l0 + M1;
    int p0 = 0, p1 = 0;
    unsigned long long k0 = mk_key(v_s[l0], i_s[l0]);
    unsigned long long k1 = mk_key(v_s[l1], i_s[l1]);
    for (int r = 0; r < QK; ++r) {
      unsigned long long me = k0 > k1 ? k0 : k1;
      unsigned long long km = me;
#pragma unroll
      for (int st = 1; st < 32; st <<= 1) {
        unsigned long long k2 = __shfl_xor(km, st);
        km = k2 > km ? k2 : km;
      }
      if (lane32 == r)
        ct_s[qtr * QK + r] = (int)(0xFFFFFFFFu - (unsigned)(km & 0xFFFFFFFFull));
      if (me == km) {  // unique keys -> exactly one owner
        if (k0 >= k1) {
          ++p0; k0 = (p0 < M1) ? mk_key(v_s[l0 + p0], i_s[l0 + p0]) : 0ull;
        } else {
          ++p1; k1 = (p1 < M1) ? mk_key(v_s[l1 + p1], i_s[l1 + p1]) : 0ull;
        }
      }
    }
  }
  __syncthreads();
  // --- fp64 re-score of 64 candidates (identical arithmetic to validated) ---
  double myv = -1e300; int myt = 0x7fffffff;
  if (threadIdx.x < NCAND) {
    myt = ct_s[threadIdx.x];
    double s = 0.0;
#pragma unroll
    for (int g = 0; g < 3; ++g) {
      const double* qp = q + ((((size_t)g * NB) + b) * NC + c) * 4;
      const float4 pv = *reinterpret_cast<const float4*>(
          ps + ((((size_t)g * NT) + myt) * NC + c) * 4);
      double pp0 = pv.x, pp1 = pv.y, pp2 = pv.z, pp3 = pv.w;
      double ss = pp0 * pp0 + pp1 * pp1 + pp2 * pp2 + pp3 * pp3;
      double dot = qp[0] * pp0 + qp[1] * pp1 + qp[2] * pp2 + qp[3] * pp3;
      s += dot / fmax(sqrt(ss), 1e-12);
    }
    myv = s * (1.0 / 3.0);
    rv_s[threadIdx.x] = myv;
  }
  __syncthreads();
  // --- rank by counting (v desc, t asc); ranks unique since t unique ---
  int rank = -1;
  if (threadIdx.x < NCAND) {
    rank = 0;
    for (int j = 0; j < NCAND; ++j) {
      double vj = rv_s[j]; int tj = ct_s[j];
      rank += (vj > myv) || (vj == myv && tj < myt);
    }
    if (rank == 0) m0_s = myv;
  }
  __syncthreads();
  if (rank >= 0 && rank < TOPM) { e_s[rank] = exp((myv - m0_s) * 10.0); ts_s[rank] = myt; }
  __syncthreads();
  if (threadIdx.x == 0) {
    double sum = 0.0;
#pragma unroll
    for (int m = 0; m < TOPM; ++m) sum += e_s[m];
    inv_s = 1.0 / sum;
  }
  __syncthreads();
  // --- emit top-20 sorted by t ascending (DRAM locality; t's unique) ---
  if (threadIdx.x < TOPM) {
    const int t = ts_s[threadIdx.x];
    int pos = 0;
#pragma unroll
    for (int j = 0; j < TOPM; ++j) pos += (ts_s[j] < t);
    w2_s[pos] = (float)(e_s[threadIdx.x] * inv_s);
    t2_s[pos] = t;
  }
  __syncthreads();
  // --- scattered gather (y mostly L3-resident across graph replays) ---
  const int p = threadIdx.x;
  if (p < NP) {
    float acc = 0.f;
#pragma unroll
    for (int m = 0; m < TOPM; ++m)
      acc += w2_s[m] * y[(((size_t)t2_s[m]) * NP + p) * NC + c];
    out[(((size_t)b * NP) + p) * NC + c] = acc;
  }
}

// ---------------------------------------------------------------------------
// Fallback (small ws): round-1-proven all-fp64 inline path.
// ---------------------------------------------------------------------------
__global__ __launch_bounds__(256) void sim_topk_inline_kernel(
    const float* __restrict__ ps, const double* __restrict__ q,
    double* __restrict__ cval, int* __restrict__ cidx, int nch, int chunk) {
  const int wav = threadIdx.x >> 6;
  const int c = threadIdx.x & 63;
  const int b = blockIdx.y * 4 + wav;
  const int ch = blockIdx.x;
  double qv[3][4];
#pragma unroll
  for (int g = 0; g < 3; ++g) {
    const double* qp = q + ((((size_t)g * NB) + b) * NC + c) * 4;
    qv[g][0] = qp[0]; qv[g][1] = qp[1]; qv[g][2] = qp[2]; qv[g][3] = qp[3];
  }
  double val[TOPM]; int idx[TOPM];
#pragma unroll
  for (int m = 0; m < TOPM; ++m) { val[m] = -1e300; idx[m] = 0; }
  int t0 = ch * chunk;
  int t1 = t0 + chunk; if (t1 > NT) t1 = NT;
  for (int t = t0; t < t1; ++t) {
    double s = 0.0;
#pragma unroll
    for (int g = 0; g < 3; ++g) {
      const float4 pv = *reinterpret_cast<const float4*>(
          ps + ((((size_t)g * NT) + t) * NC + c) * 4);
      double p0 = pv.x, p1 = pv.y, p2 = pv.z, p3 = pv.w;
      double ss = p0 * p0 + p1 * p1 + p2 * p2 + p3 * p3;
      double dot = qv[g][0] * p0 + qv[g][1] * p1 + qv[g][2] * p2 + qv[g][3] * p3;
      s += dot / fmax(sqrt(ss), 1e-12);
    }
    s *= (1.0 / 3.0);
    if (s > val[TOPM - 1]) {
      double cv = s; int ci = t;
#pragma unroll
      for (int m = 0; m < TOPM; ++m) {
        bool sw = cv > val[m];
        double tv = sw ? val[m] : cv; int ti = sw ? idx[m] : ci;
        val[m] = sw ? cv : val[m];    idx[m] = sw ? ci : idx[m];
        cv = tv; ci = ti;
      }
    }
  }
  double* vout = cval + ((((size_t)b * NC) + c) * nch + ch) * TOPM;
  int* iout = cidx + ((((size_t)b * NC) + c) * nch + ch) * TOPM;
#pragma unroll
  for (int m = 0; m < TOPM; ++m) { vout[m] = val[m]; iout[m] = idx[m]; }
}

__global__ __launch_bounds__(128) void merge_gather_old_kernel(
    const double* __restrict__ cval, const int* __restrict__ cidx,
    const float* __restrict__ y, float* __restrict__ out, int nch) {
  const int c = blockIdx.x;
  const int b = blockIdx.y;
  __shared__ float w_s[TOPM];
  __shared__ int i_s[TOPM];
  if (threadIdx.x == 0) {
    double val[TOPM]; int idx[TOPM];
#pragma unroll
    for (int m = 0; m < TOPM; ++m) { val[m] = -1e300; idx[m] = 0; }
    const double* vin = cval + (((size_t)b * NC) + c) * nch * TOPM;
    const int* iin = cidx + (((size_t)b * NC) + c) * nch * TOPM;
    for (int k = 0; k < nch; ++k) {
      const int base = k * TOPM;
      for (int m = 0; m < TOPM; ++m) {
        double s = vin[base + m];
        if (!(s > val[TOPM - 1])) break;
        double cv = s; int ci = iin[base + m];
#pragma unroll
        for (int mm = 0; mm < TOPM; ++mm) {
          bool sw = cv > val[mm];
          double tv = sw ? val[mm] : cv; int ti = sw ? idx[mm] : ci;
          val[mm] = sw ? cv : val[mm];   idx[mm] = sw ? ci : idx[mm];
          cv = tv; ci = ti;
        }
      }
    }
    double mx = val[0];
    double e[TOPM]; double sum = 0.0;
#pragma unroll
    for (int m = 0; m < TOPM; ++m) { e[m] = exp((val[m] - mx) * 10.0); sum += e[m]; }
    double inv = 1.0 / sum;
#pragma unroll
    for (int m = 0; m < TOPM; ++m) { w_s[m] = (float)(e[m] * inv); i_s[m] = idx[m]; }
  }
  __syncthreads();
  const int p = threadIdx.x;
  if (p < NP) {
    float acc = 0.f;
#pragma unroll
    for (int m = 0; m < TOPM; ++m)
      acc += w_s[m] * y[(((size_t)i_s[m]) * NP + p) * NC + c];
    out[(((size_t)b * NP) + p) * NC + c] = acc;
  }
}

extern "C" void kernel_launch(void* const* d_in, const int* in_sizes, int n_in,
                              void* d_out, int out_size, void* d_ws, size_t ws_size,
                              hipStream_t stream) {
  const float* x = (const float*)d_in[0];
  const float* ps = (const float*)d_in[1];
  const float* y = (const float*)d_in[2];
  float* out = (float*)d_out;
  char* ws = (char*)d_ws;

  const size_t qbytes = (size_t)NG * NB * NC * 4 * sizeof(double);        // 196,608
  const size_t phat16bytes = (size_t)NG * NT * NC * 8;                    // 15.36 MB
  const size_t cvalbytes = (size_t)NB * NC * NCH * M1 * sizeof(float);    // 16.78 MB
  const size_t cidxbytes = cvalbytes;                                     // 16.78 MB

  double* qbuf = (double*)ws;

  if (ws_size >= qbytes + phat16bytes + cvalbytes + cidxbytes) {
    uint2* phat16 = (uint2*)(ws + qbytes);
    float* cval = (float*)(ws + qbytes + phat16bytes);
    int* cidx = (int*)((char*)cval + cvalbytes);
    pre_kernel<<<dim3(NB + PNBLK), dim3(512), 0, stream>>>(x, ps, qbuf, phat16);
    sim32_kernel<<<dim3(NB / 16, NCH), dim3(1024), 0, stream>>>(phat16, qbuf,
                                                                cval, cidx);
    merge_gather_kernel<<<dim3(NC, NB), dim3(128), 0, stream>>>(cval, cidx, ps,
                                                                qbuf, y, out);
  } else {
    // fallback: round-1-proven all-fp64 path (pre runs qstat class only)
    pre_kernel<<<dim3(NB), dim3(512), 0, stream>>>(x, ps, qbuf, (uint2*)nullptr);
    const size_t per_ch = (size_t)NB * NC * TOPM * (sizeof(double) + sizeof(int));
    int nch = 1;
    if (ws_size > qbytes) {
      size_t mc = (ws_size - qbytes) / per_ch;
      nch = mc < 32 ? (int)mc : 32;
      if (nch < 1) nch = 1;
    }
    const int chunk = (NT + nch - 1) / nch;
    double* fcval = (double*)(ws + qbytes);
    int* fcidx = (int*)((char*)fcval + (size_t)NB * NC * nch * TOPM * sizeof(double));
    sim_topk_inline_kernel<<<dim3(nch, NB / 4), dim3(256), 0, stream>>>(
        ps, qbuf, fcval, fcidx, nch, chunk);
    merge_gather_old_kernel<<<dim3(NC, NB), dim3(128), 0, stream>>>(fcval, fcidx, y,
                                                                    out, nch);
  }
}

// Round 14
// 117.249 us; speedup vs baseline: 1.8889x; 1.2295x over previous
//
#include <hip/hip_runtime.h>
#include <hip/hip_fp16.h>
#include <math.h>

#define NB 32
#define NL 512
#define NC 64
#define NG 3
#define NT 10000
#define NP 96
#define TOPM 20
#define M1 8      // per-lane per-chunk prefilter list
#define NCH 256   // t-chunks (250 real, 6 empty)
#define CHUNK 40
#define QK 16     // extracted per quarter (4 quarters -> 64 candidates)
#define NCAND 64
#define PNBLK 1250   // pnorm blocks (NT*NC/512)
#define NENT (NB * NC * TOPM)  // 40960 selected entries
#define BINCAP 64    // fixed bin capacity (P(Poisson(4.1)>64) ~ 1e-50)
#define P16STR ((size_t)NT * NC)  // uint2 stride between g-planes of phat16

union H2U { uint2 u; __half2 h[2]; };

// ---------------------------------------------------------------------------
// Kernel 1 (pre, R13-proven): [0,NB) qstat | [NB,..) pnorm -> fp16 phat16.
// ---------------------------------------------------------------------------
__global__ __launch_bounds__(512) void pre_kernel(const float* __restrict__ x,
                                                  const float* __restrict__ ps,
                                                  double* __restrict__ q,
                                                  uint2* __restrict__ phat16) {
  __shared__ double s_sum[8][3][64], s_sq[8][3][64], s_abs[8][3][64];
  __shared__ double s_first[3][64], s_last[3][64];
  if (blockIdx.x < NB) {
    const int b = blockIdx.x, w = threadIdx.x >> 6, c = threadIdx.x & 63;
    const float* xp = x + (size_t)b * NL * NC + c;
    const int l0 = w * 64;
    double sum[3] = {0, 0, 0}, sumsq[3] = {0, 0, 0}, sumabs[3] = {0, 0, 0};
    double prev[3] = {0, 0, 0}, first[3] = {0, 0, 0};
    if (w > 0) {
      double e0 = xp[(l0 - 4) * NC], e1 = xp[(l0 - 3) * NC];
      double e2 = xp[(l0 - 2) * NC], e3 = xp[(l0 - 1) * NC];
      prev[2] = e3; prev[1] = (e2 + e3) * 0.5; prev[0] = (e0 + e1 + e2 + e3) * 0.25;
    }
    double acc2 = 0.0, acc4 = 0.0;
    for (int i = 0; i < 64; ++i) {
      const int l = l0 + i;
      double v = (double)xp[l * NC];
      sum[2] += v; sumsq[2] += v * v;
      if (l == 0) first[2] = v; else sumabs[2] += fabs(v - prev[2]);
      prev[2] = v;
      acc2 += v;
      if (l & 1) {
        double cur = acc2 * 0.5; acc2 = 0.0;
        sum[1] += cur; sumsq[1] += cur * cur;
        if (l == 1) first[1] = cur; else sumabs[1] += fabs(cur - prev[1]);
        prev[1] = cur;
      }
      acc4 += v;
      if ((l & 3) == 3) {
        double cur = acc4 * 0.25; acc4 = 0.0;
        sum[0] += cur; sumsq[0] += cur * cur;
        if (l == 3) first[0] = cur; else sumabs[0] += fabs(cur - prev[0]);
        prev[0] = cur;
      }
    }
    for (int g = 0; g < 3; ++g) {
      s_sum[w][g][c] = sum[g]; s_sq[w][g][c] = sumsq[g]; s_abs[w][g][c] = sumabs[g];
    }
    if (w == 0) { for (int g = 0; g < 3; ++g) s_first[g][c] = first[g]; }
    if (w == 7) { for (int g = 0; g < 3; ++g) s_last[g][c] = prev[g]; }
    __syncthreads();
    if (w == 0) {
      const double J[3] = {128.0, 256.0, 512.0};
      for (int g = 0; g < 3; ++g) {
        double S = 0, Q2 = 0, A = 0;
        for (int ww = 0; ww < 8; ++ww) {
          S += s_sum[ww][g][c]; Q2 += s_sq[ww][g][c]; A += s_abs[ww][g][c];
        }
        double mean = S / J[g];
        double var = Q2 / J[g] - mean * mean; if (var < 0.0) var = 0.0;
        double last = s_last[g][c];
        double s0 = mean - last;
        double s1 = sqrt(var);
        double s2 = (last - s_first[g][c]) * (1.0 / 511.0);
        double s3 = A * (1.0 / 511.0);
        double n = sqrt(s0 * s0 + s1 * s1 + s2 * s2 + s3 * s3);
        double inv = 1.0 / fmax(n, 1e-12);
        double* qp = q + ((((size_t)g * NB) + b) * NC + c) * 4;
        qp[0] = s0 * inv; qp[1] = s1 * inv; qp[2] = s2 * inv; qp[3] = s3 * inv;
      }
    }
  } else {
    const int i = (blockIdx.x - NB) * 512 + threadIdx.x;  // over T*C
    if (i < NT * NC) {
#pragma unroll
      for (int g = 0; g < 3; ++g) {
        const size_t off = ((size_t)g * NT * NC + i) * 4;
        const float4 pv = *reinterpret_cast<const float4*>(ps + off);
        double p0 = pv.x, p1 = pv.y, p2 = pv.z, p3 = pv.w;
        double inv = 1.0 / fmax(sqrt(p0 * p0 + p1 * p1 + p2 * p2 + p3 * p3), 1e-12);
        H2U o;
        o.h[0] = __halves2half2(__float2half_rn((float)(p0 * inv)),
                                __float2half_rn((float)(p1 * inv)));
        o.h[1] = __halves2half2(__float2half_rn((float)(p2 * inv)),
                                __float2half_rn((float)(p3 * inv)));
        phat16[(size_t)g * P16STR + i] = o.u;
      }
    }
  }
}

// packed key: (ordermap16(fp16(v)) << 16) | (0xFFFF - t); u32-desc == (v desc, t asc)
__device__ __forceinline__ unsigned mkkey16(float v, int t) {
  unsigned h = (unsigned)__half_as_ushort(__float2half_rn(v));
  h = (h & 0x8000u) ? ((~h) & 0xFFFFu) : (h | 0x8000u);
  return (h << 16) | (0xFFFFu - (unsigned)t);
}

__device__ __forceinline__ void insert8k(unsigned k, unsigned key[M1]) {
  unsigned cv = k;
#pragma unroll
  for (int m = 0; m < M1; ++m) {
    bool sw = cv > key[m];
    unsigned tv = sw ? key[m] : cv;
    key[m] = sw ? cv : key[m];
    cv = tv;
  }
}

#if defined(__has_builtin)
#if __has_builtin(__builtin_amdgcn_fdot2)
#define HAVE_FDOT2 1
#endif
#endif

__device__ __forceinline__ float sim_dot(const uint2* __restrict__ p16,
                                         size_t o,
#ifdef HAVE_FDOT2
                                         const __half2 qh[6]
#else
                                         const float qv[12]
#endif
                                         ) {
  H2U a0, a1, a2;
  a0.u = p16[o];
  a1.u = p16[P16STR + o];
  a2.u = p16[2 * P16STR + o];
#ifdef HAVE_FDOT2
  float s = 0.f;
  s = __builtin_amdgcn_fdot2(qh[0], a0.h[0], s, false);
  s = __builtin_amdgcn_fdot2(qh[1], a0.h[1], s, false);
  s = __builtin_amdgcn_fdot2(qh[2], a1.h[0], s, false);
  s = __builtin_amdgcn_fdot2(qh[3], a1.h[1], s, false);
  s = __builtin_amdgcn_fdot2(qh[4], a2.h[0], s, false);
  s = __builtin_amdgcn_fdot2(qh[5], a2.h[1], s, false);
  return s;
#else
  float2 f0 = __half22float2(a0.h[0]), f1 = __half22float2(a0.h[1]);
  float2 f2 = __half22float2(a1.h[0]), f3 = __half22float2(a1.h[1]);
  float2 f4 = __half22float2(a2.h[0]), f5 = __half22float2(a2.h[1]);
  return qv[0] * f0.x + qv[1] * f0.y + qv[2] * f1.x + qv[3] * f1.y +
         qv[4] * f2.x + qv[5] * f2.y + qv[6] * f3.x + qv[7] * f3.y +
         qv[8] * f4.x + qv[9] * f4.y + qv[10] * f5.x + qv[11] * f5.y;
#endif
}

// ---------------------------------------------------------------------------
// Kernel 2: prefilter scan -> per-(row,chunk) top-8 packed u32 keys (32B).
// R6-proven shape: 1024 thr = 16 b-waves sharing chunk stream; grid (2,NCH);
// LB(1024,8). Blocks (0, y<10) zero the t-histogram (stream-ordered).
// ---------------------------------------------------------------------------
__global__ __launch_bounds__(1024, 8) void sim32_kernel(
    const uint2* __restrict__ p16, const double* __restrict__ q,
    unsigned* __restrict__ ckey, int* __restrict__ hist) {
  if (blockIdx.x == 0 && blockIdx.y < 10) {
    const int idx = blockIdx.y * 1024 + threadIdx.x;
    if (idx < NT) hist[idx] = 0;
  }
  const int wav = threadIdx.x >> 6;
  const int c = threadIdx.x & 63;
  const int b = blockIdx.x * 16 + wav;
  const int ch = blockIdx.y;
#ifdef HAVE_FDOT2
  __half2 qh[6];
#pragma unroll
  for (int g = 0; g < 3; ++g) {
    const double* qp = q + ((((size_t)g * NB) + b) * NC + c) * 4;
    qh[g * 2 + 0] = __halves2half2(__float2half_rn((float)(qp[0] * (1.0 / 3.0))),
                                   __float2half_rn((float)(qp[1] * (1.0 / 3.0))));
    qh[g * 2 + 1] = __halves2half2(__float2half_rn((float)(qp[2] * (1.0 / 3.0))),
                                   __float2half_rn((float)(qp[3] * (1.0 / 3.0))));
  }
#else
  float qv[12];
#pragma unroll
  for (int g = 0; g < 3; ++g) {
    const double* qp = q + ((((size_t)g * NB) + b) * NC + c) * 4;
#pragma unroll
    for (int j = 0; j < 4; ++j) qv[g * 4 + j] = (float)(qp[j] * (1.0 / 3.0));
  }
#endif
  unsigned key[M1];
#pragma unroll
  for (int m = 0; m < M1; ++m) key[m] = 0u;
  int t0 = ch * CHUNK;
  int t1 = t0 + CHUNK; if (t1 > NT) t1 = NT;
  for (int t = t0; t + 1 < t1; t += 2) {
    const size_t oA = (size_t)t * NC + c;
    const size_t oB = oA + NC;
#ifdef HAVE_FDOT2
    const float sA = sim_dot(p16, oA, qh);
    const float sB = sim_dot(p16, oB, qh);
#else
    const float sA = sim_dot(p16, oA, qv);
    const float sB = sim_dot(p16, oB, qv);
#endif
    const unsigned kA = mkkey16(sA, t);
    const unsigned kB = mkkey16(sB, t + 1);
    if (kA > key[M1 - 1]) insert8k(kA, key);
    if (kB > key[M1 - 1]) insert8k(kB, key);
  }
  unsigned* ko = ckey + ((((size_t)b * NC) + c) * NCH + ch) * M1;
  *reinterpret_cast<uint4*>(ko) = make_uint4(key[0], key[1], key[2], key[3]);
  *reinterpret_cast<uint4*>(ko + 4) = make_uint4(key[4], key[5], key[6], key[7]);
}

// ---------------------------------------------------------------------------
// Kernel 3: merge (u32-key quarter extraction) + fp64 rerank (validated
// arithmetic, raw ps) + softmax -> (w,t) per row + DIRECT fixed-capacity
// binning (atomicAdd on hist, no scan/scatter). Block = (c,b), 128 threads.
// ---------------------------------------------------------------------------
__global__ __launch_bounds__(128) void merge_rerank_kernel(
    const unsigned* __restrict__ ckey, const float* __restrict__ ps,
    const double* __restrict__ q, float* __restrict__ w_out,
    int* __restrict__ t_out, int* __restrict__ hist, int* __restrict__ bin_slot) {
  const int c = blockIdx.x, b = blockIdx.y;
  __shared__ unsigned k_s[NCH * M1];   // 8 KB
  __shared__ int ct_s[NCAND];
  __shared__ double rv_s[NCAND];
  __shared__ double m0_s, inv_s;
  __shared__ double e_s[TOPM];
  __shared__ int ts_s[TOPM];
  const int n = NCH * M1;  // 2048
  const size_t row = (size_t)b * NC + c;
  const uint4* kin = reinterpret_cast<const uint4*>(ckey + row * n);
  for (int k = threadIdx.x; k < n / 4; k += 128)
    *reinterpret_cast<uint4*>(&k_s[k * 4]) = kin[k];
  __syncthreads();
  // --- quarter extraction: quarter = (w<<1)|(lane>>5), 2 lists/lane ---
  {
    const int w = threadIdx.x >> 6, lane = threadIdx.x & 63;
    const int lane32 = lane & 31;
    const int qtr = (w << 1) | (lane >> 5);
    const int l0 = (qtr * 64 + lane32 * 2) * M1;
    const int l1 = l0 + M1;
    int p0 = 0, p1 = 0;
    unsigned k0 = k_s[l0], k1 = k_s[l1];
    for (int r = 0; r < QK; ++r) {
      const unsigned me = k0 > k1 ? k0 : k1;
      unsigned km = me;
#pragma unroll
      for (int st = 1; st < 32; st <<= 1) {
        const unsigned k2 = __shfl_xor(km, st);
        km = k2 > km ? k2 : km;
      }
      if (lane32 == r) ct_s[qtr * QK + r] = (int)(0xFFFFu - (km & 0xFFFFu));
      if (me == km) {  // unique keys -> exactly one owner
        if (k0 >= k1) { ++p0; k0 = (p0 < M1) ? k_s[l0 + p0] : 0u; }
        else          { ++p1; k1 = (p1 < M1) ? k_s[l1 + p1] : 0u; }
      }
    }
  }
  __syncthreads();
  // --- fp64 re-score of 64 candidates (identical arithmetic to validated) ---
  double myv = -1e300; int myt = 0x7fffffff;
  if (threadIdx.x < NCAND) {
    myt = ct_s[threadIdx.x];
    double s = 0.0;
#pragma unroll
    for (int g = 0; g < 3; ++g) {
      const double* qp = q + ((((size_t)g * NB) + b) * NC + c) * 4;
      const float4 pv = *reinterpret_cast<const float4*>(
          ps + ((((size_t)g * NT) + myt) * NC + c) * 4);
      double pp0 = pv.x, pp1 = pv.y, pp2 = pv.z, pp3 = pv.w;
      double ss = pp0 * pp0 + pp1 * pp1 + pp2 * pp2 + pp3 * pp3;
      double dot = qp[0] * pp0 + qp[1] * pp1 + qp[2] * pp2 + qp[3] * pp3;
      s += dot / fmax(sqrt(ss), 1e-12);
    }
    myv = s * (1.0 / 3.0);
    rv_s[threadIdx.x] = myv;
  }
  __syncthreads();
  // --- rank by counting (v desc, t asc); unique since t unique ---
  int rank = -1;
  if (threadIdx.x < NCAND) {
    rank = 0;
    for (int j = 0; j < NCAND; ++j) {
      double vj = rv_s[j]; int tj = ct_s[j];
      rank += (vj > myv) || (vj == myv && tj < myt);
    }
    if (rank == 0) m0_s = myv;
  }
  __syncthreads();
  if (rank >= 0 && rank < TOPM) { e_s[rank] = exp((myv - m0_s) * 10.0); ts_s[rank] = myt; }
  __syncthreads();
  if (threadIdx.x == 0) {
    double sum = 0.0;
#pragma unroll
    for (int m = 0; m < TOPM; ++m) sum += e_s[m];
    inv_s = 1.0 / sum;
  }
  __syncthreads();
  if (threadIdx.x < TOPM) {
    const int t = ts_s[threadIdx.x];
    const int i = (int)(row * TOPM) + threadIdx.x;
    w_out[i] = (float)(e_s[threadIdx.x] * inv_s);
    t_out[i] = t;
    const int pos = atomicAdd(&hist[t], 1);
    if (pos < BINCAP) bin_slot[t * BINCAP + pos] = i;
  }
}

// ---------------------------------------------------------------------------
// Kernel 4: one block per t, 256 thr. Stage y[t] (24KB CONTIGUOUS) into LDS
// (65-float stride: bank (p+c)%32, 2-way = free); serve k entries, 2 at a
// time via thread-halves. partial[i][p] = w_i * y[t][p][c_i]. Deterministic:
// each entry owns its partial slot.
// ---------------------------------------------------------------------------
__global__ __launch_bounds__(256) void process_kernel(
    const float* __restrict__ y, const int* __restrict__ hist,
    const int* __restrict__ bin_slot, const float* __restrict__ w_out,
    float* __restrict__ partial) {
  const int t = blockIdx.x;
  int k = hist[t];
  if (k == 0) return;
  if (k > BINCAP) k = BINCAP;
  __shared__ float lds[NP * 65];   // 24,960 B
  __shared__ float w_l[BINCAP];
  __shared__ int i_l[BINCAP];
  __shared__ int c_l[BINCAP];
  const float4* yrow = reinterpret_cast<const float4*>(y + (size_t)t * NP * NC);
#pragma unroll
  for (int r = 0; r < 6; ++r) {
    const int e4 = threadIdx.x + r * 256;
    const float4 v = yrow[e4];
    const int p = e4 >> 4;
    const int c = (e4 & 15) * 4;
    lds[p * 65 + c] = v.x; lds[p * 65 + c + 1] = v.y;
    lds[p * 65 + c + 2] = v.z; lds[p * 65 + c + 3] = v.w;
  }
  if (threadIdx.x < k) {
    const int i = bin_slot[t * BINCAP + threadIdx.x];
    i_l[threadIdx.x] = i;
    w_l[threadIdx.x] = w_out[i];
    c_l[threadIdx.x] = (i / TOPM) & 63;
  }
  __syncthreads();
  const int h = threadIdx.x >> 7;
  const int p = threadIdx.x & 127;
  for (int e = h; e < k; e += 2) {
    if (p < NP)
      partial[(size_t)i_l[e] * NP + p] = w_l[e] * lds[p * 65 + c_l[e]];
  }
}

// ---------------------------------------------------------------------------
// Kernel 5: out[b][p][c] = sum_m partial[row*20+m][p], fixed m order.
// ---------------------------------------------------------------------------
__global__ __launch_bounds__(128) void final_kernel(const float* __restrict__ partial,
                                                    float* __restrict__ out) {
  const int row = blockIdx.x;
  const int p = threadIdx.x;
  if (p >= NP) return;
  const int b = row >> 6, c = row & 63;
  const float* pp = partial + (size_t)row * TOPM * NP + p;
  float acc = 0.f;
#pragma unroll
  for (int m = 0; m < TOPM; ++m) acc += pp[m * NP];
  out[(((size_t)b * NP) + p) * NC + c] = acc;
}

// ---------------------------------------------------------------------------
// Fallback (small ws): round-1-proven all-fp64 inline path.
// ---------------------------------------------------------------------------
__global__ __launch_bounds__(256) void sim_topk_inline_kernel(
    const float* __restrict__ ps, const double* __restrict__ q,
    double* __restrict__ cval, int* __restrict__ cidx, int nch, int chunk) {
  const int wav = threadIdx.x >> 6;
  const int c = threadIdx.x & 63;
  const int b = blockIdx.y * 4 + wav;
  const int ch = blockIdx.x;
  double qv[3][4];
#pragma unroll
  for (int g = 0; g < 3; ++g) {
    const double* qp = q + ((((size_t)g * NB) + b) * NC + c) * 4;
    qv[g][0] = qp[0]; qv[g][1] = qp[1]; qv[g][2] = qp[2]; qv[g][3] = qp[3];
  }
  double val[TOPM]; int idx[TOPM];
#pragma unroll
  for (int m = 0; m < TOPM; ++m) { val[m] = -1e300; idx[m] = 0; }
  int t0 = ch * chunk;
  int t1 = t0 + chunk; if (t1 > NT) t1 = NT;
  for (int t = t0; t < t1; ++t) {
    double s = 0.0;
#pragma unroll
    for (int g = 0; g < 3; ++g) {
      const float4 pv = *reinterpret_cast<const float4*>(
          ps + ((((size_t)g * NT) + t) * NC + c) * 4);
      double p0 = pv.x, p1 = pv.y, p2 = pv.z, p3 = pv.w;
      double ss = p0 * p0 + p1 * p1 + p2 * p2 + p3 * p3;
      double dot = qv[g][0] * p0 + qv[g][1] * p1 + qv[g][2] * p2 + qv[g][3] * p3;
      s += dot / fmax(sqrt(ss), 1e-12);
    }
    s *= (1.0 / 3.0);
    if (s > val[TOPM - 1]) {
      double cv = s; int ci = t;
#pragma unroll
      for (int m = 0; m < TOPM; ++m) {
        bool sw = cv > val[m];
        double tv = sw ? val[m] : cv; int ti = sw ? idx[m] : ci;
        val[m] = sw ? cv : val[m];    idx[m] = sw ? ci : idx[m];
        cv = tv; ci = ti;
      }
    }
  }
  double* vout = cval + ((((size_t)b * NC) + c) * nch + ch) * TOPM;
  int* iout = cidx + ((((size_t)b * NC) + c) * nch + ch) * TOPM;
#pragma unroll
  for (int m = 0; m < TOPM; ++m) { vout[m] = val[m]; iout[m] = idx[m]; }
}

__global__ __launch_bounds__(128) void merge_gather_old_kernel(
    const double* __restrict__ cval, const int* __restrict__ cidx,
    const float* __restrict__ y, float* __restrict__ out, int nch) {
  const int c = blockIdx.x;
  const int b = blockIdx.y;
  __shared__ float w_s[TOPM];
  __shared__ int i_s[TOPM];
  if (threadIdx.x == 0) {
    double val[TOPM]; int idx[TOPM];
#pragma unroll
    for (int m = 0; m < TOPM; ++m) { val[m] = -1e300; idx[m] = 0; }
    const double* vin = cval + (((size_t)b * NC) + c) * nch * TOPM;
    const int* iin = cidx + (((size_t)b * NC) + c) * nch * TOPM;
    for (int k = 0; k < nch; ++k) {
      const int base = k * TOPM;
      for (int m = 0; m < TOPM; ++m) {
        double s = vin[base + m];
        if (!(s > val[TOPM - 1])) break;
        double cv = s; int ci = iin[base + m];
#pragma unroll
        for (int mm = 0; mm < TOPM; ++mm) {
          bool sw = cv > val[mm];
          double tv = sw ? val[mm] : cv; int ti = sw ? idx[mm] : ci;
          val[mm] = sw ? cv : val[mm];   idx[mm] = sw ? ci : idx[mm];
          cv = tv; ci = ti;
        }
      }
    }
    double mx = val[0];
    double e[TOPM]; double sum = 0.0;
#pragma unroll
    for (int m = 0; m < TOPM; ++m) { e[m] = exp((val[m] - mx) * 10.0); sum += e[m]; }
    double inv = 1.0 / sum;
#pragma unroll
    for (int m = 0; m < TOPM; ++m) { w_s[m] = (float)(e[m] * inv); i_s[m] = idx[m]; }
  }
  __syncthreads();
  const int p = threadIdx.x;
  if (p < NP) {
    float acc = 0.f;
#pragma unroll
    for (int m = 0; m < TOPM; ++m)
      acc += w_s[m] * y[(((size_t)i_s[m]) * NP + p) * NC + c];
    out[(((size_t)b * NP) + p) * NC + c] = acc;
  }
}

extern "C" void kernel_launch(void* const* d_in, const int* in_sizes, int n_in,
                              void* d_out, int out_size, void* d_ws, size_t ws_size,
                              hipStream_t stream) {
  const float* x = (const float*)d_in[0];
  const float* ps = (const float*)d_in[1];
  const float* y = (const float*)d_in[2];
  float* out = (float*)d_out;
  char* ws = (char*)d_ws;

  const size_t qbytes = (size_t)NG * NB * NC * 4 * sizeof(double);      // 196,608
  const size_t phat16bytes = (size_t)NG * NT * NC * 8;                  // 15.36 MB
  const size_t ckeybytes = (size_t)NB * NC * NCH * M1 * 4;              // 16.78 MB
  const size_t wtbytes = (size_t)NENT * 4;                              // 163,840
  const size_t histbytes = (size_t)NT * 4;                              // 40,000
  const size_t slotbytes = (size_t)NT * BINCAP * 4;                     // 2.56 MB
  const size_t partbytes = (size_t)NENT * NP * 4;                       // 15.73 MB

  double* qbuf = (double*)ws;
  size_t off = qbytes;
  uint2* phat16 = (uint2*)(ws + off); off += phat16bytes;
  unsigned* ckey = (unsigned*)(ws + off); off += ckeybytes;
  float* w_out = (float*)(ws + off); off += wtbytes;
  int* t_out = (int*)(ws + off); off += wtbytes;
  int* hist = (int*)(ws + off); off += histbytes;
  off = (off + 7) & ~(size_t)7;
  int* bin_slot = (int*)(ws + off); off += slotbytes;
  float* partial = (float*)(ws + off); off += partbytes;

  if (ws_size >= off) {
    pre_kernel<<<dim3(NB + PNBLK), dim3(512), 0, stream>>>(x, ps, qbuf, phat16);
    sim32_kernel<<<dim3(NB / 16, NCH), dim3(1024), 0, stream>>>(phat16, qbuf,
                                                                ckey, hist);
    merge_rerank_kernel<<<dim3(NC, NB), dim3(128), 0, stream>>>(
        ckey, ps, qbuf, w_out, t_out, hist, bin_slot);
    process_kernel<<<dim3(NT), dim3(256), 0, stream>>>(y, hist, bin_slot,
                                                       w_out, partial);
    final_kernel<<<dim3(NB * NC), dim3(128), 0, stream>>>(partial, out);
  } else {
    // fallback: round-1-proven all-fp64 path (pre runs qstat class only)
    pre_kernel<<<dim3(NB), dim3(512), 0, stream>>>(x, ps, qbuf, (uint2*)nullptr);
    const size_t per_ch = (size_t)NB * NC * TOPM * (sizeof(double) + sizeof(int));
    int nch = 1;
    if (ws_size > qbytes) {
      size_t mc = (ws_size - qbytes) / per_ch;
      nch = mc < 32 ? (int)mc : 32;
      if (nch < 1) nch = 1;
    }
    const int chunk = (NT + nch - 1) / nch;
    double* fcval = (double*)(ws + qbytes);
    int* fcidx = (int*)((char*)fcval + (size_t)NB * NC * nch * TOPM * sizeof(double));
    sim_topk_inline_kernel<<<dim3(nch, NB / 4), dim3(256), 0, stream>>>(
        ps, qbuf, fcval, fcidx, nch, chunk);
    merge_gather_old_kernel<<<dim3(NC, NB), dim3(128), 0, stream>>>(fcval, fcidx, y,
                                                                    out, nch);
  }
}